// Round 12
// baseline (813.269 us; speedup 1.0000x reference)
//
#include <hip/hip_runtime.h>
#include <hip/hip_bf16.h>

#define BATCH 2
#define SEQ 2048
#define HID 4096
#define NHEAD 32
#define HDIM 128
#define BH (BATCH*NHEAD)   /* 64 */
#define MROWS (BATCH*SEQ)  /* 4096 */
#define SC2 0.1275187963f   /* (1/sqrt(128)) * log2(e), folded into Q in rope */

typedef __attribute__((ext_vector_type(8))) short bf16x8;
typedef __attribute__((ext_vector_type(4))) float f32x4;

__device__ __forceinline__ float bf2f(short x){
  union { float f; unsigned u; } v; v.u = ((unsigned)(unsigned short)x) << 16; return v.f;
}
__device__ __forceinline__ short f2bf(float f){
  union { float f; unsigned u; } v; v.f = f;
  unsigned r = v.u + 0x7fffu + ((v.u >> 16) & 1u);
  return (short)(r >> 16);
}
__device__ __forceinline__ void gload_lds16(const void* g, void* l){
  __builtin_amdgcn_global_load_lds(
    (const __attribute__((address_space(1))) void*)g,
    (__attribute__((address_space(3))) void*)l, 16, 0, 0);
}

// ---------------- fused f32 -> bf16 convert (3 tensors) ----------------
__global__ void cvt3_bf16(const float* __restrict__ a, short* __restrict__ ao, int na4,
                          const float* __restrict__ b, short* __restrict__ bo, int nb4,
                          const float* __restrict__ cc, short* __restrict__ co, int nc4){
  int i = blockIdx.x*blockDim.x + threadIdx.x;
  int stride = gridDim.x*blockDim.x;
  int tot = na4 + nb4 + nc4;
  for (; i < tot; i += stride){
    const float* src; short* dst; int k = i;
    if (k < na4){ src=a; dst=ao; }
    else if (k < na4+nb4){ k -= na4; src=b; dst=bo; }
    else { k -= na4+nb4; src=cc; dst=co; }
    float4 v = ((const float4*)src)[k];
    short4 o;
    o.x = f2bf(v.x); o.y = f2bf(v.y); o.z = f2bf(v.z); o.w = f2bf(v.w);
    ((short4*)dst)[k] = o;
  }
}

// ---------------- RoPE cos/sin table ----------------
__global__ void rope_table_k(const int* __restrict__ pos, float* __restrict__ tab){
  int idx = blockIdx.x*blockDim.x + threadIdx.x;
  if (idx >= SEQ*64) return;
  int s = idx >> 6, d = idx & 63;
  float p = (float)pos[s];
  float inv = exp2f(-(float)d * (13.287712379549449f/64.0f)); // 10000^(-d/64)
  float ang = p * inv;
  tab[2*idx]   = cosf(ang);
  tab[2*idx+1] = sinf(ang);
}

// ===== 256x256 8-phase GEMM; reads = r5 known-good {12,4,8,0}; stages evened to
// exactly one half-tile (2 gload) per phase; vmcnt(6) at ph4 AND ph8.
// Ledger: in-flight peaks 14; vmcnt(6)@ph4 drains {prev ph6,7,8, ph1} = buf1 tile;
// vmcnt(6)@ph8 drains {ph2,3,4,5} = buf0 tile. Every WAR crosses >=1 barrier. =====
template<int W>
__device__ __forceinline__ void stage_half(const short* __restrict__ gsrc, int ldg,
                                           short* lds, int tid, int h){
  #pragma unroll
  for (int li=0; li<2; ++li){
    int e16 = li*512 + tid;
    int rs = e16 >> 3, ck = e16 & 7;
    int r = ((rs/W)*2 + h)*W + (rs%W);
    gload_lds16(gsrc + (size_t)r*ldg + ((ck ^ (r&7))<<3),
                lds + r*64 + ck*8);
  }
}

__device__ __forceinline__ void read_ahalf(const short* Asb, int wr, int c, int g,
                                           int Mh, bf16x8 (&afr)[4][2]){
  #pragma unroll
  for (int mi=0; mi<4; ++mi){
    int row = wr*128 + (Mh*4+mi)*16 + c;
    const char* bp = (const char*)Asb + row*128;
    #pragma unroll
    for (int kk=0; kk<2; ++kk)
      afr[mi][kk] = *(const bf16x8*)(bp + ((kk*64 + g*16) ^ ((row&7)<<4)));
  }
}
__device__ __forceinline__ void read_bhalf(const short* Bsb, int wc, int c, int g,
                                           int Nh, bf16x8 (&bfr)[2][2]){
  #pragma unroll
  for (int ni=0; ni<2; ++ni){
    int row = wc*64 + (Nh*2+ni)*16 + c;
    const char* bp = (const char*)Bsb + row*128;
    #pragma unroll
    for (int kk=0; kk<2; ++kk)
      bfr[ni][kk] = *(const bf16x8*)(bp + ((kk*64 + g*16) ^ ((row&7)<<4)));
  }
}
template<int MH, int NHH>
__device__ __forceinline__ void mma_q(bf16x8 (&afr)[4][2], bf16x8 (&bfr)[2][2],
                                      f32x4 (&acc)[8][4]){
  #pragma unroll
  for (int kk=0; kk<2; ++kk)
    #pragma unroll
    for (int mi=0; mi<4; ++mi)
      #pragma unroll
      for (int ni=0; ni<2; ++ni)
        acc[MH*4+mi][NHH*2+ni] = __builtin_amdgcn_mfma_f32_16x16x32_bf16(
            afr[mi][kk], bfr[ni][kk], acc[MH*4+mi][NHH*2+ni], 0,0,0);
}

#define BAR()  asm volatile("s_barrier" ::: "memory")
#define LGK0() asm volatile("s_waitcnt lgkmcnt(0)" ::: "memory")
#define VMC6() asm volatile("s_waitcnt vmcnt(6)" ::: "memory")
#define VMC0() asm volatile("s_waitcnt vmcnt(0)" ::: "memory")
#define SP1()  __builtin_amdgcn_s_setprio(1)
#define SP0()  __builtin_amdgcn_s_setprio(0)

// MODE 0: QKV proj -> clip +-8 -> scatter bf16 into Q/K/V [BH][S][HD]
// MODE 1: O proj -> f32 row-major out
template<int MODE>
__global__ __launch_bounds__(512, 2) void gemm8u(
    const short* __restrict__ A, const short* __restrict__ Bw,
    short* __restrict__ Qb, short* __restrict__ Kb, short* __restrict__ Vb,
    float* __restrict__ Of){
  __shared__ __align__(16) short As[2][256*64];
  __shared__ __align__(16) short Bs[2][256*64];
  const int K = HID;
  int tid = threadIdx.x, lane = tid & 63, w = tid >> 6;
  int wr = w >> 2, wc = w & 3, g = lane >> 4, c = lane & 15;
  int gx = gridDim.x;
  int nwg = gx * gridDim.y;
  int bid = blockIdx.y*gx + blockIdx.x;
  int cpx = nwg >> 3;
  int swz = (bid & 7)*cpx + (bid >> 3);
  int m0 = (swz / gx) * 256, n0 = (swz % gx) * 256;

  const short* Abase = A  + (size_t)m0*K;
  const short* Bbase = Bw + (size_t)n0*K;
  auto stageA = [&](int buf, int kt, int h){
    stage_half<64>(Abase + kt*64, K, &As[buf][0], tid, h);
  };
  auto stageB = [&](int buf, int kt, int h){
    stage_half<32>(Bbase + kt*64, K, &Bs[buf][0], tid, h);
  };

  f32x4 acc[8][4];
  f32x4 zero = {0.f,0.f,0.f,0.f};
  #pragma unroll
  for (int i=0;i<8;++i)
    #pragma unroll
    for (int j=0;j<4;++j) acc[i][j] = zero;
  bf16x8 afr[4][2], bfr0[2][2], bfr1[2][2];

  // prologue: t0 fully (8 loads) + t1's Bh0,Bh1,Ah0 (6 loads); drain t0
  stageB(0,0,0); stageB(0,0,1); stageA(0,0,0); stageA(0,0,1);
  stageB(1,1,0); stageB(1,1,1); stageA(1,1,0);
  VMC6();   // 14 in flight -> drain 8 oldest = t0 complete; t1's 6 remain
  BAR();

  const int NITER = K/128;  // 32 iterations, 2 K-tiles each
  for (int i = 0; i < NITER-1; ++i){
    int t1 = 2*i+1, t2 = 2*i+2, t3 = 2*i+3;
    // ph1: reads A0h0+B0N0; stage A(t1)h1 [deferred from prev iter]
    read_ahalf(&As[0][0], wr,c,g, 0, afr);
    read_bhalf(&Bs[0][0], wc,c,g, 0, bfr0);
    stageA(1, t1, 1);
    BAR(); LGK0(); SP1(); mma_q<0,0>(afr,bfr0,acc); SP0(); BAR();
    // ph2: reads B0N1; stage B(t2)h0
    read_bhalf(&Bs[0][0], wc,c,g, 1, bfr1);
    stageB(0, t2, 0);
    BAR(); LGK0(); SP1(); mma_q<0,1>(afr,bfr1,acc); SP0(); BAR();
    // ph3: reads A0h1; stage B(t2)h1
    read_ahalf(&As[0][0], wr,c,g, 1, afr);
    stageB(0, t2, 1);
    BAR(); LGK0(); SP1(); mma_q<1,1>(afr,bfr1,acc); SP0(); BAR();
    // ph4: stage A(t2)h0; vmcnt(6) -> t1 (buf1) fully landed
    stageA(0, t2, 0);
    BAR(); LGK0(); SP1(); mma_q<1,0>(afr,bfr0,acc); SP0(); VMC6(); BAR();
    // ph5: reads A1h0+B1N0; stage A(t2)h1
    read_ahalf(&As[1][0], wr,c,g, 0, afr);
    read_bhalf(&Bs[1][0], wc,c,g, 0, bfr0);
    stageA(0, t2, 1);
    BAR(); LGK0(); SP1(); mma_q<0,0>(afr,bfr0,acc); SP0(); BAR();
    // ph6: reads B1N1; stage B(t3)h0
    read_bhalf(&Bs[1][0], wc,c,g, 1, bfr1);
    stageB(1, t3, 0);
    BAR(); LGK0(); SP1(); mma_q<0,1>(afr,bfr1,acc); SP0(); BAR();
    // ph7: reads A1h1; stage B(t3)h1
    read_ahalf(&As[1][0], wr,c,g, 1, afr);
    stageB(1, t3, 1);
    BAR(); LGK0(); SP1(); mma_q<1,1>(afr,bfr1,acc); SP0(); BAR();
    // ph8: stage A(t3)h0; vmcnt(6) -> t2 (buf0) fully landed
    stageA(1, t3, 0);
    BAR(); LGK0(); SP1(); mma_q<1,0>(afr,bfr0,acc); SP0(); VMC6(); BAR();
  }
  { // peeled final iteration (tiles NT-2 buf0, NT-1 buf1)
    int t1 = 2*(NITER-1)+1;
    read_ahalf(&As[0][0], wr,c,g, 0, afr);
    read_bhalf(&Bs[0][0], wc,c,g, 0, bfr0);
    stageA(1, t1, 1);   // last stage: A(NT-1)h1
    BAR(); LGK0(); SP1(); mma_q<0,0>(afr,bfr0,acc); SP0(); BAR();
    read_bhalf(&Bs[0][0], wc,c,g, 1, bfr1);
    BAR(); LGK0(); SP1(); mma_q<0,1>(afr,bfr1,acc); SP0(); BAR();
    read_ahalf(&As[0][0], wr,c,g, 1, afr);
    BAR(); LGK0(); SP1(); mma_q<1,1>(afr,bfr1,acc); SP0(); BAR();
    BAR(); LGK0(); SP1(); mma_q<1,0>(afr,bfr0,acc); SP0(); VMC0(); BAR();
    read_ahalf(&As[1][0], wr,c,g, 0, afr);
    read_bhalf(&Bs[1][0], wc,c,g, 0, bfr0);
    BAR(); LGK0(); SP1(); mma_q<0,0>(afr,bfr0,acc); SP0(); BAR();
    read_bhalf(&Bs[1][0], wc,c,g, 1, bfr1);
    BAR(); LGK0(); SP1(); mma_q<0,1>(afr,bfr1,acc); SP0(); BAR();
    read_ahalf(&As[1][0], wr,c,g, 1, afr);
    BAR(); LGK0(); SP1(); mma_q<1,1>(afr,bfr1,acc); SP0(); BAR();
    BAR(); LGK0(); SP1(); mma_q<1,0>(afr,bfr0,acc); SP0(); BAR();
  }

  // epilogue
  #pragma unroll
  for (int fa=0; fa<8; ++fa){
    #pragma unroll
    for (int fb=0; fb<4; ++fb){
      f32x4 v = acc[fa][fb];
      #pragma unroll
      for (int rr=0; rr<4; ++rr){
        int row = m0 + wr*128 + fa*16 + g*4 + rr;
        int col = n0 + wc*64  + fb*16 + c;
        float x = v[rr];
        if (MODE == 0){
          x = fminf(fmaxf(x, -8.0f), 8.0f);
          int sel = col >> 12, wi = col & 4095;
          int head = wi >> 7, d = wi & 127;
          int b = row >> 11, s = row & 2047;
          size_t off = ((size_t)(b*NHEAD + head)*SEQ + s)*HDIM + d;
          short* dst = (sel == 0) ? Qb : (sel == 1) ? Kb : Vb;
          dst[off] = f2bf(x);
        } else {
          Of[(size_t)row*HID + col] = x;
        }
      }
    }
  }
}

// ---- RoPE in place on Q and K, vectorized; Q gets *SC2 (scale+log2e fold) ----
__global__ void rope_apply_k(short* __restrict__ Qb, short* __restrict__ Kb,
                             const float* __restrict__ tab){
  int idx = blockIdx.x*blockDim.x + threadIdx.x;
  if (idx >= BH*SEQ*8) return;
  int t = idx & 7;
  int s = (idx >> 3) & (SEQ-1);
  int bh = idx >> 14;
  size_t base = ((size_t)bh*SEQ + s)*HDIM + t*8;
  const float* tb = tab + 2*(s*64 + t*8);
  bf16x8 q1 = *(bf16x8*)(Qb+base), q2 = *(bf16x8*)(Qb+base+64);
  bf16x8 k1 = *(bf16x8*)(Kb+base), k2 = *(bf16x8*)(Kb+base+64);
  bf16x8 o1, o2, p1, p2;
  #pragma unroll
  for (int u=0;u<8;++u){
    float cs = tb[2*u], sn = tb[2*u+1];
    float a = bf2f(q1[u]), b = bf2f(q2[u]);
    o1[u] = f2bf((a*cs - b*sn)*SC2); o2[u] = f2bf((b*cs + a*sn)*SC2);
    a = bf2f(k1[u]); b = bf2f(k2[u]);
    p1[u] = f2bf(a*cs - b*sn); p2[u] = f2bf(b*cs + a*sn);
  }
  *(bf16x8*)(Qb+base)    = o1; *(bf16x8*)(Qb+base+64) = o2;
  *(bf16x8*)(Kb+base)    = p1; *(bf16x8*)(Kb+base+64) = p2;
}

// ---------------- V transpose: [BH][S][HD] -> Vt [BH][HD][S] ----------------
__global__ void transpose_v_k(const short* __restrict__ V, short* __restrict__ Vt){
  __shared__ short t[32][33];
  int bh = blockIdx.z;
  int s0 = blockIdx.x*32, d0 = blockIdx.y*32;
  int tx = threadIdx.x & 31, ty = threadIdx.x >> 5;  // 32 x 8
  const short* src = V + ((size_t)bh*SEQ + s0)*HDIM + d0;
  #pragma unroll
  for (int i=ty;i<32;i+=8) t[i][tx] = src[(size_t)i*HDIM + tx];
  __syncthreads();
  short* dst = Vt + ((size_t)bh*HDIM + d0)*SEQ + s0;
  #pragma unroll
  for (int i=ty;i<32;i+=8) dst[(size_t)i*SEQ + tx] = t[tx][i];
}

// ---- Flash attention, causal, double-buffered; SWAPPED QK^T (S^T in regs):
// lane (g,c) holds S[q=c][kv=fj*16+g*4+rr] -> row softmax = in-reg tree + 2 shfls.
// Ps[i][j] = P[q=i][kv=j]; Ps writes packed as short4 (b64, 2-way bank = free). ----
__global__ __launch_bounds__(256) void flash_attn_k(
    const short* __restrict__ Qb, const short* __restrict__ Kb,
    const short* __restrict__ Vt, short* __restrict__ attn){
  __shared__ short Ks[2][64*128];   // [kv][d], chunk-swizzled
  __shared__ short Vs[2][128*64];   // [d][kv], chunk-swizzled
  __shared__ short Ps[4][16][72];   // per-wave P, padded stride 72
  int tid = threadIdx.x, lane = tid & 63, w = tid >> 6;
  int g = lane >> 4, c = lane & 15;
  int flat = blockIdx.y*gridDim.x + blockIdx.x;
  int xcd = flat & 7, idx = flat >> 3;
  int bh = xcd + 8*(idx >> 5);
  int qblk = 31 - (idx & 31);       // heavy-first
  int q0 = qblk * 64;
  int qw = q0 + w*16;
  bf16x8 qf[4];
  #pragma unroll
  for (int ks=0;ks<4;++ks)
    qf[ks] = *(const bf16x8*)(Qb + ((size_t)bh*SEQ + qw + c)*HDIM + ks*32 + g*8);
  f32x4 o[8];
  f32x4 zero = {0.f,0.f,0.f,0.f};
  #pragma unroll
  for (int i=0;i<8;++i) o[i] = zero;
  float m_r = -1e30f;   // running max for q-row = qw + c
  float l_r = 0.f;      // running denom

  auto stage = [&](int j, int b){
    int kv0 = j*64;
    #pragma unroll
    for (int i=0;i<4;++i){
      int e = i*256 + tid;
      int kr = e >> 4, kc = e & 15;
      gload_lds16(Kb + ((size_t)bh*SEQ + kv0 + kr)*HDIM + (size_t)((kc ^ (kr&7))*8),
                  &Ks[b][kr*128 + kc*8]);
      int vr = e >> 3, vc = e & 7;
      gload_lds16(Vt + ((size_t)bh*HDIM + vr)*SEQ + kv0 + (size_t)((vc ^ (vr&7))*8),
                  &Vs[b][vr*64 + vc*8]);
    }
  };

  stage(0, 0);
  __syncthreads();
  int buf = 0;
  for (int j=0;j<=qblk;++j){
    if (j < qblk) stage(j+1, buf^1);

    int kv0 = j*64;
    f32x4 sf[4];
    #pragma unroll
    for (int fj=0;fj<4;++fj) sf[fj] = zero;
    __builtin_amdgcn_s_setprio(1);
    #pragma unroll
    for (int ks=0;ks<4;++ks){
      #pragma unroll
      for (int fj=0;fj<4;++fj){
        int kvrow = fj*16 + c;
        bf16x8 kb = *(const bf16x8*)&Ks[buf][kvrow*128 + (((ks*4+g) ^ (c&7))*8)];
        sf[fj] = __builtin_amdgcn_mfma_f32_16x16x32_bf16(kb, qf[ks], sf[fj], 0,0,0);
      }
    }
    __builtin_amdgcn_s_setprio(0);
    if (j == qblk){
      int q = qw + c;
      #pragma unroll
      for (int fj=0;fj<4;++fj)
        #pragma unroll
        for (int rr=0;rr<4;++rr)
          if ((kv0 + fj*16 + g*4 + rr) > q) sf[fj][rr] = -1e30f;
    }
    f32x4 t4;
    #pragma unroll
    for (int rr=0;rr<4;++rr)
      t4[rr] = fmaxf(fmaxf(sf[0][rr], sf[1][rr]), fmaxf(sf[2][rr], sf[3][rr]));
    float rmax = fmaxf(fmaxf(t4[0], t4[1]), fmaxf(t4[2], t4[3]));
    rmax = fmaxf(rmax, __shfl_xor(rmax, 16));
    rmax = fmaxf(rmax, __shfl_xor(rmax, 32));
    if (__any(rmax > m_r + 8.0f)){
      float mnew = fmaxf(m_r, rmax);
      float alpha = exp2f(m_r - mnew);
      m_r = mnew;
      l_r *= alpha;
      float a4[4];
      #pragma unroll
      for (int rr=0;rr<4;++rr) a4[rr] = __shfl(alpha, g*4 + rr);
      #pragma unroll
      for (int ni=0;ni<8;++ni){
        f32x4 t = o[ni];
        t[0]*=a4[0]; t[1]*=a4[1]; t[2]*=a4[2]; t[3]*=a4[3];
        o[ni] = t;
      }
    }
    float ps;
    {
      f32x4 s4;
      #pragma unroll
      for (int fj=0;fj<4;++fj)
        #pragma unroll
        for (int rr=0;rr<4;++rr)
          sf[fj][rr] = exp2f(sf[fj][rr] - m_r);
      #pragma unroll
      for (int rr=0;rr<4;++rr)
        s4[rr] = (sf[0][rr] + sf[1][rr]) + (sf[2][rr] + sf[3][rr]);
      ps = (s4[0] + s4[1]) + (s4[2] + s4[3]);
      ps += __shfl_xor(ps, 16);
      ps += __shfl_xor(ps, 32);
    }
    l_r += ps;
    // P -> Ps, packed 4 bf16 per b64 store (lane holds q=c, kv=fj*16+g*4+rr)
    #pragma unroll
    for (int fj=0;fj<4;++fj){
      short4 pk;
      pk.x = f2bf(sf[fj][0]); pk.y = f2bf(sf[fj][1]);
      pk.z = f2bf(sf[fj][2]); pk.w = f2bf(sf[fj][3]);
      *(short4*)&Ps[w][c][fj*16 + g*4] = pk;
    }
    __builtin_amdgcn_s_setprio(1);
    #pragma unroll
    for (int ks=0;ks<2;++ks){
      bf16x8 pa = *(const bf16x8*)&Ps[w][c][ks*32 + g*8];
      #pragma unroll
      for (int ni=0;ni<8;++ni){
        int d = ni*16 + c;
        bf16x8 vb = *(const bf16x8*)&Vs[buf][d*64 + (((ks*4+g) ^ (c&7))*8)];
        o[ni] = __builtin_amdgcn_mfma_f32_16x16x32_bf16(pa, vb, o[ni], 0,0,0);
      }
    }
    __builtin_amdgcn_s_setprio(0);
    __syncthreads();
    buf ^= 1;
  }
  int b = bh >> 5, h = bh & 31;
  float inv = 1.0f / l_r;
  float inv4[4];
  #pragma unroll
  for (int rr=0;rr<4;++rr) inv4[rr] = __shfl(inv, g*4 + rr);
  #pragma unroll
  for (int rr=0;rr<4;++rr){
    int s = qw + g*4 + rr;
    #pragma unroll
    for (int ni=0;ni<8;++ni){
      int d = ni*16 + c;
      attn[((size_t)(b*SEQ + s))*HID + h*HDIM + d] = f2bf(o[ni][rr] * inv4[rr]);
    }
  }
}

extern "C" void kernel_launch(void* const* d_in, const int* in_sizes, int n_in,
                              void* d_out, int out_size, void* d_ws, size_t ws_size,
                              hipStream_t stream){
  const float* hs   = (const float*)d_in[0];
  const int*   pos  = (const int*)d_in[1];
  const float* wqkv = (const float*)d_in[2];
  const float* wo   = (const float*)d_in[3];
  float* out = (float*)d_out;
  char* ws = (char*)d_ws;
  size_t off = 0;
  auto alloc = [&](size_t bytes){ void* p = ws + off; off += (bytes + 255) & ~(size_t)255; return p; };
  short* hsb   = (short*)alloc((size_t)MROWS*HID*2);
  short* wqkvb = (short*)alloc((size_t)3*HID*HID*2);
  short* wob   = (short*)alloc((size_t)HID*HID*2);
  short* Qb    = (short*)alloc((size_t)BH*SEQ*HDIM*2);
  short* Kb    = (short*)alloc((size_t)BH*SEQ*HDIM*2);
  short* Vb    = (short*)alloc((size_t)BH*SEQ*HDIM*2);
  short* Vt    = (short*)alloc((size_t)BH*SEQ*HDIM*2);
  short* attn  = (short*)alloc((size_t)MROWS*HID*2);
  float* tab   = (float*)alloc((size_t)SEQ*64*2*4);
  (void)ws_size; (void)in_sizes; (void)n_in; (void)out_size;

  cvt3_bf16<<<2048,256,0,stream>>>(hs, hsb, MROWS*HID/4,
                                   wqkv, wqkvb, 3*HID*HID/4,
                                   wo, wob, HID*HID/4);
  rope_table_k<<<(SEQ*64+255)/256,256,0,stream>>>(pos, tab);
  gemm8u<0><<<dim3(48,16),512,0,stream>>>(hsb, wqkvb, Qb, Kb, Vb, nullptr);
  rope_apply_k<<<(BH*SEQ*8+255)/256,256,0,stream>>>(Qb, Kb, tab);
  transpose_v_k<<<dim3(SEQ/32, HDIM/32, BH),256,0,stream>>>(Vb, Vt);
  flash_attn_k<<<dim3(SEQ/64, BH),256,0,stream>>>(Qb, Kb, Vt, attn);
  gemm8u<1><<<dim3(16,16),512,0,stream>>>(attn, wob, nullptr, nullptr, nullptr, out);
}

// Round 13
// 784.661 us; speedup vs baseline: 1.0365x; 1.0365x over previous
//
#include <hip/hip_runtime.h>
#include <hip/hip_bf16.h>

#define BATCH 2
#define SEQ 2048
#define HID 4096
#define NHEAD 32
#define HDIM 128
#define BH (BATCH*NHEAD)   /* 64 */
#define MROWS (BATCH*SEQ)  /* 4096 */
#define SC2 0.1275187963f   /* (1/sqrt(128)) * log2(e), folded into Q in rope */

typedef __attribute__((ext_vector_type(8))) short bf16x8;
typedef __attribute__((ext_vector_type(4))) float f32x4;

__device__ __forceinline__ float bf2f(short x){
  union { float f; unsigned u; } v; v.u = ((unsigned)(unsigned short)x) << 16; return v.f;
}
__device__ __forceinline__ short f2bf(float f){
  union { float f; unsigned u; } v; v.f = f;
  unsigned r = v.u + 0x7fffu + ((v.u >> 16) & 1u);
  return (short)(r >> 16);
}
__device__ __forceinline__ void gload_lds16(const void* g, void* l){
  __builtin_amdgcn_global_load_lds(
    (const __attribute__((address_space(1))) void*)g,
    (__attribute__((address_space(3))) void*)l, 16, 0, 0);
}

// ---------------- fused f32 -> bf16 convert (3 tensors) ----------------
__global__ void cvt3_bf16(const float* __restrict__ a, short* __restrict__ ao, int na4,
                          const float* __restrict__ b, short* __restrict__ bo, int nb4,
                          const float* __restrict__ cc, short* __restrict__ co, int nc4){
  int i = blockIdx.x*blockDim.x + threadIdx.x;
  int stride = gridDim.x*blockDim.x;
  int tot = na4 + nb4 + nc4;
  for (; i < tot; i += stride){
    const float* src; short* dst; int k = i;
    if (k < na4){ src=a; dst=ao; }
    else if (k < na4+nb4){ k -= na4; src=b; dst=bo; }
    else { k -= na4+nb4; src=cc; dst=co; }
    float4 v = ((const float4*)src)[k];
    short4 o;
    o.x = f2bf(v.x); o.y = f2bf(v.y); o.z = f2bf(v.z); o.w = f2bf(v.w);
    ((short4*)dst)[k] = o;
  }
}

// ---------------- RoPE cos/sin table ----------------
__global__ void rope_table_k(const int* __restrict__ pos, float* __restrict__ tab){
  int idx = blockIdx.x*blockDim.x + threadIdx.x;
  if (idx >= SEQ*64) return;
  int s = idx >> 6, d = idx & 63;
  float p = (float)pos[s];
  float inv = exp2f(-(float)d * (13.287712379549449f/64.0f)); // 10000^(-d/64)
  float ang = p * inv;
  tab[2*idx]   = cosf(ang);
  tab[2*idx+1] = sinf(ang);
}

// ===== 256x256 8-phase GEMM, minimal LDS reads (24 b128/K-tile), vmcnt(6/8) =====
// (round-5 known-good: 395us QKV, MfmaUtil 45.6, 0 bank conflicts, no spill.
//  Verified local optimum: r4 collapse, r7 spill, r9 {8,0,8,8} -7%, r12 evened -4%.)
template<int W>
__device__ __forceinline__ void stage_half(const short* __restrict__ gsrc, int ldg,
                                           short* lds, int tid, int h){
  #pragma unroll
  for (int li=0; li<2; ++li){
    int e16 = li*512 + tid;
    int rs = e16 >> 3, ck = e16 & 7;
    int r = ((rs/W)*2 + h)*W + (rs%W);
    gload_lds16(gsrc + (size_t)r*ldg + ((ck ^ (r&7))<<3),
                lds + r*64 + ck*8);
  }
}

__device__ __forceinline__ void read_ahalf(const short* Asb, int wr, int c, int g,
                                           int Mh, bf16x8 (&afr)[4][2]){
  #pragma unroll
  for (int mi=0; mi<4; ++mi){
    int row = wr*128 + (Mh*4+mi)*16 + c;
    const char* bp = (const char*)Asb + row*128;
    #pragma unroll
    for (int kk=0; kk<2; ++kk)
      afr[mi][kk] = *(const bf16x8*)(bp + ((kk*64 + g*16) ^ ((row&7)<<4)));
  }
}
__device__ __forceinline__ void read_bhalf(const short* Bsb, int wc, int c, int g,
                                           int Nh, bf16x8 (&bfr)[2][2]){
  #pragma unroll
  for (int ni=0; ni<2; ++ni){
    int row = wc*64 + (Nh*2+ni)*16 + c;
    const char* bp = (const char*)Bsb + row*128;
    #pragma unroll
    for (int kk=0; kk<2; ++kk)
      bfr[ni][kk] = *(const bf16x8*)(bp + ((kk*64 + g*16) ^ ((row&7)<<4)));
  }
}
template<int MH, int NHH>
__device__ __forceinline__ void mma_q(bf16x8 (&afr)[4][2], bf16x8 (&bfr)[2][2],
                                      f32x4 (&acc)[8][4]){
  #pragma unroll
  for (int kk=0; kk<2; ++kk)
    #pragma unroll
    for (int mi=0; mi<4; ++mi)
      #pragma unroll
      for (int ni=0; ni<2; ++ni)
        acc[MH*4+mi][NHH*2+ni] = __builtin_amdgcn_mfma_f32_16x16x32_bf16(
            afr[mi][kk], bfr[ni][kk], acc[MH*4+mi][NHH*2+ni], 0,0,0);
}

#define BAR()  asm volatile("s_barrier" ::: "memory")
#define LGK0() asm volatile("s_waitcnt lgkmcnt(0)" ::: "memory")
#define VMC6() asm volatile("s_waitcnt vmcnt(6)" ::: "memory")
#define VMC8() asm volatile("s_waitcnt vmcnt(8)" ::: "memory")
#define VMC0() asm volatile("s_waitcnt vmcnt(0)" ::: "memory")
#define SP1()  __builtin_amdgcn_s_setprio(1)
#define SP0()  __builtin_amdgcn_s_setprio(0)

// MODE 0: QKV proj -> clip +-8 -> scatter bf16 into Q/K/V [BH][S][HD]
// MODE 1: O proj -> f32 row-major out
template<int MODE>
__global__ __launch_bounds__(512, 2) void gemm8r(
    const short* __restrict__ A, const short* __restrict__ Bw,
    short* __restrict__ Qb, short* __restrict__ Kb, short* __restrict__ Vb,
    float* __restrict__ Of){
  __shared__ __align__(16) short As[2][256*64];
  __shared__ __align__(16) short Bs[2][256*64];
  const int K = HID;
  int tid = threadIdx.x, lane = tid & 63, w = tid >> 6;
  int wr = w >> 2, wc = w & 3, g = lane >> 4, c = lane & 15;
  int gx = gridDim.x;
  int nwg = gx * gridDim.y;
  int bid = blockIdx.y*gx + blockIdx.x;
  int cpx = nwg >> 3;
  int swz = (bid & 7)*cpx + (bid >> 3);
  int m0 = (swz / gx) * 256, n0 = (swz % gx) * 256;

  const short* Abase = A  + (size_t)m0*K;
  const short* Bbase = Bw + (size_t)n0*K;
  auto stageA = [&](int buf, int kt, int h){
    stage_half<64>(Abase + kt*64, K, &As[buf][0], tid, h);
  };
  auto stageB = [&](int buf, int kt, int h){
    stage_half<32>(Bbase + kt*64, K, &Bs[buf][0], tid, h);
  };

  f32x4 acc[8][4];
  f32x4 zero = {0.f,0.f,0.f,0.f};
  #pragma unroll
  for (int i=0;i<8;++i)
    #pragma unroll
    for (int j=0;j<4;++j) acc[i][j] = zero;
  bf16x8 afr[4][2], bfr0[2][2], bfr1[2][2];

  stageB(0,0,0); stageB(0,0,1); stageA(0,0,0); stageA(0,0,1);
  stageB(1,1,0); stageB(1,1,1); stageA(1,1,0); stageA(1,1,1);
  VMC8();
  BAR();

  const int NITER = K/128;  // 32 iterations, 2 K-tiles each
  for (int i = 0; i < NITER-1; ++i){
    int t2 = 2*i+2, t3 = 2*i+3;
    read_ahalf(&As[0][0], wr,c,g, 0, afr);
    read_bhalf(&Bs[0][0], wc,c,g, 0, bfr0);
    BAR(); LGK0(); SP1(); mma_q<0,0>(afr,bfr0,acc); SP0(); BAR();
    read_bhalf(&Bs[0][0], wc,c,g, 1, bfr1);
    stageB(0, t2, 0);
    BAR(); LGK0(); SP1(); mma_q<0,1>(afr,bfr1,acc); SP0(); BAR();
    read_ahalf(&As[0][0], wr,c,g, 1, afr);
    stageB(0, t2, 1); stageA(0, t2, 0);
    BAR(); LGK0(); SP1(); mma_q<1,1>(afr,bfr1,acc); SP0(); BAR();
    BAR(); LGK0(); SP1(); mma_q<1,0>(afr,bfr0,acc); SP0(); VMC6(); BAR();
    read_ahalf(&As[1][0], wr,c,g, 0, afr);
    read_bhalf(&Bs[1][0], wc,c,g, 0, bfr0);
    stageA(0, t2, 1);
    BAR(); LGK0(); SP1(); mma_q<0,0>(afr,bfr0,acc); SP0(); BAR();
    read_bhalf(&Bs[1][0], wc,c,g, 1, bfr1);
    stageB(1, t3, 0);
    BAR(); LGK0(); SP1(); mma_q<0,1>(afr,bfr1,acc); SP0(); BAR();
    read_ahalf(&As[1][0], wr,c,g, 1, afr);
    stageB(1, t3, 1); stageA(1, t3, 0);
    BAR(); LGK0(); SP1(); mma_q<1,1>(afr,bfr1,acc); SP0(); BAR();
    stageA(1, t3, 1);
    BAR(); LGK0(); SP1(); mma_q<1,0>(afr,bfr0,acc); SP0(); VMC8(); BAR();
  }
  {
    read_ahalf(&As[0][0], wr,c,g, 0, afr);
    read_bhalf(&Bs[0][0], wc,c,g, 0, bfr0);
    BAR(); LGK0(); SP1(); mma_q<0,0>(afr,bfr0,acc); SP0(); BAR();
    read_bhalf(&Bs[0][0], wc,c,g, 1, bfr1);
    BAR(); LGK0(); SP1(); mma_q<0,1>(afr,bfr1,acc); SP0(); BAR();
    read_ahalf(&As[0][0], wr,c,g, 1, afr);
    BAR(); LGK0(); SP1(); mma_q<1,1>(afr,bfr1,acc); SP0(); BAR();
    BAR(); LGK0(); SP1(); mma_q<1,0>(afr,bfr0,acc); SP0(); VMC0(); BAR();
    read_ahalf(&As[1][0], wr,c,g, 0, afr);
    read_bhalf(&Bs[1][0], wc,c,g, 0, bfr0);
    BAR(); LGK0(); SP1(); mma_q<0,0>(afr,bfr0,acc); SP0(); BAR();
    read_bhalf(&Bs[1][0], wc,c,g, 1, bfr1);
    BAR(); LGK0(); SP1(); mma_q<0,1>(afr,bfr1,acc); SP0(); BAR();
    read_ahalf(&As[1][0], wr,c,g, 1, afr);
    BAR(); LGK0(); SP1(); mma_q<1,1>(afr,bfr1,acc); SP0(); BAR();
    BAR(); LGK0(); SP1(); mma_q<1,0>(afr,bfr0,acc); SP0(); BAR();
  }

  #pragma unroll
  for (int fa=0; fa<8; ++fa){
    #pragma unroll
    for (int fb=0; fb<4; ++fb){
      f32x4 v = acc[fa][fb];
      #pragma unroll
      for (int rr=0; rr<4; ++rr){
        int row = m0 + wr*128 + fa*16 + g*4 + rr;
        int col = n0 + wc*64  + fb*16 + c;
        float x = v[rr];
        if (MODE == 0){
          x = fminf(fmaxf(x, -8.0f), 8.0f);
          int sel = col >> 12, wi = col & 4095;
          int head = wi >> 7, d = wi & 127;
          int b = row >> 11, s = row & 2047;
          size_t off = ((size_t)(b*NHEAD + head)*SEQ + s)*HDIM + d;
          short* dst = (sel == 0) ? Qb : (sel == 1) ? Kb : Vb;
          dst[off] = f2bf(x);
        } else {
          Of[(size_t)row*HID + col] = x;
        }
      }
    }
  }
}

// ---- RoPE in place on Q and K, vectorized; Q gets *SC2 (scale+log2e fold) ----
__global__ void rope_apply_k(short* __restrict__ Qb, short* __restrict__ Kb,
                             const float* __restrict__ tab){
  int idx = blockIdx.x*blockDim.x + threadIdx.x;
  if (idx >= BH*SEQ*8) return;
  int t = idx & 7;
  int s = (idx >> 3) & (SEQ-1);
  int bh = idx >> 14;
  size_t base = ((size_t)bh*SEQ + s)*HDIM + t*8;
  const float* tb = tab + 2*(s*64 + t*8);
  bf16x8 q1 = *(bf16x8*)(Qb+base), q2 = *(bf16x8*)(Qb+base+64);
  bf16x8 k1 = *(bf16x8*)(Kb+base), k2 = *(bf16x8*)(Kb+base+64);
  bf16x8 o1, o2, p1, p2;
  #pragma unroll
  for (int u=0;u<8;++u){
    float cs = tb[2*u], sn = tb[2*u+1];
    float a = bf2f(q1[u]), b = bf2f(q2[u]);
    o1[u] = f2bf((a*cs - b*sn)*SC2); o2[u] = f2bf((b*cs + a*sn)*SC2);
    a = bf2f(k1[u]); b = bf2f(k2[u]);
    p1[u] = f2bf(a*cs - b*sn); p2[u] = f2bf(b*cs + a*sn);
  }
  *(bf16x8*)(Qb+base)    = o1; *(bf16x8*)(Qb+base+64) = o2;
  *(bf16x8*)(Kb+base)    = p1; *(bf16x8*)(Kb+base+64) = p2;
}

// ---------------- V transpose: [BH][S][HD] -> Vt [BH][HD][S] ----------------
__global__ void transpose_v_k(const short* __restrict__ V, short* __restrict__ Vt){
  __shared__ short t[32][33];
  int bh = blockIdx.z;
  int s0 = blockIdx.x*32, d0 = blockIdx.y*32;
  int tx = threadIdx.x & 31, ty = threadIdx.x >> 5;  // 32 x 8
  const short* src = V + ((size_t)bh*SEQ + s0)*HDIM + d0;
  #pragma unroll
  for (int i=ty;i<32;i+=8) t[i][tx] = src[(size_t)i*HDIM + tx];
  __syncthreads();
  short* dst = Vt + ((size_t)bh*HDIM + d0)*SEQ + s0;
  #pragma unroll
  for (int i=ty;i<32;i+=8) dst[(size_t)i*SEQ + tx] = t[tx][i];
}

// ---- Flash attention, causal, double-buffered; SWAPPED QK^T (S^T in regs):
// lane (g,c) holds S[q=c][kv=fj*16+g*4+rr] -> row softmax = in-reg tree + 2 shfls.
// Ps[i][j] = P[q=i][kv=j]; Ps writes packed as short4 (b64, 2-way bank = free). ----
__global__ __launch_bounds__(256) void flash_attn_k(
    const short* __restrict__ Qb, const short* __restrict__ Kb,
    const short* __restrict__ Vt, short* __restrict__ attn){
  __shared__ short Ks[2][64*128];   // [kv][d], chunk-swizzled
  __shared__ short Vs[2][128*64];   // [d][kv], chunk-swizzled
  __shared__ short Ps[4][16][72];   // per-wave P, padded stride 72
  int tid = threadIdx.x, lane = tid & 63, w = tid >> 6;
  int g = lane >> 4, c = lane & 15;
  int flat = blockIdx.y*gridDim.x + blockIdx.x;
  int xcd = flat & 7, idx = flat >> 3;
  int bh = xcd + 8*(idx >> 5);
  int qblk = 31 - (idx & 31);       // heavy-first
  int q0 = qblk * 64;
  int qw = q0 + w*16;
  bf16x8 qf[4];
  #pragma unroll
  for (int ks=0;ks<4;++ks)
    qf[ks] = *(const bf16x8*)(Qb + ((size_t)bh*SEQ + qw + c)*HDIM + ks*32 + g*8);
  f32x4 o[8];
  f32x4 zero = {0.f,0.f,0.f,0.f};
  #pragma unroll
  for (int i=0;i<8;++i) o[i] = zero;
  float m_r = -1e30f;   // running max for q-row = qw + c
  float l_r = 0.f;      // running denom

  auto stage = [&](int j, int b){
    int kv0 = j*64;
    #pragma unroll
    for (int i=0;i<4;++i){
      int e = i*256 + tid;
      int kr = e >> 4, kc = e & 15;
      gload_lds16(Kb + ((size_t)bh*SEQ + kv0 + kr)*HDIM + (size_t)((kc ^ (kr&7))*8),
                  &Ks[b][kr*128 + kc*8]);
      int vr = e >> 3, vc = e & 7;
      gload_lds16(Vt + ((size_t)bh*HDIM + vr)*SEQ + kv0 + (size_t)((vc ^ (vr&7))*8),
                  &Vs[b][vr*64 + vc*8]);
    }
  };

  stage(0, 0);
  __syncthreads();
  int buf = 0;
  for (int j=0;j<=qblk;++j){
    if (j < qblk) stage(j+1, buf^1);

    int kv0 = j*64;
    f32x4 sf[4];
    #pragma unroll
    for (int fj=0;fj<4;++fj) sf[fj] = zero;
    __builtin_amdgcn_s_setprio(1);
    #pragma unroll
    for (int ks=0;ks<4;++ks){
      #pragma unroll
      for (int fj=0;fj<4;++fj){
        int kvrow = fj*16 + c;
        bf16x8 kb = *(const bf16x8*)&Ks[buf][kvrow*128 + (((ks*4+g) ^ (c&7))*8)];
        sf[fj] = __builtin_amdgcn_mfma_f32_16x16x32_bf16(kb, qf[ks], sf[fj], 0,0,0);
      }
    }
    __builtin_amdgcn_s_setprio(0);
    if (j == qblk){
      int q = qw + c;
      #pragma unroll
      for (int fj=0;fj<4;++fj)
        #pragma unroll
        for (int rr=0;rr<4;++rr)
          if ((kv0 + fj*16 + g*4 + rr) > q) sf[fj][rr] = -1e30f;
    }
    f32x4 t4;
    #pragma unroll
    for (int rr=0;rr<4;++rr)
      t4[rr] = fmaxf(fmaxf(sf[0][rr], sf[1][rr]), fmaxf(sf[2][rr], sf[3][rr]));
    float rmax = fmaxf(fmaxf(t4[0], t4[1]), fmaxf(t4[2], t4[3]));
    rmax = fmaxf(rmax, __shfl_xor(rmax, 16));
    rmax = fmaxf(rmax, __shfl_xor(rmax, 32));
    if (__any(rmax > m_r + 8.0f)){
      float mnew = fmaxf(m_r, rmax);
      float alpha = exp2f(m_r - mnew);
      m_r = mnew;
      l_r *= alpha;
      float a4[4];
      #pragma unroll
      for (int rr=0;rr<4;++rr) a4[rr] = __shfl(alpha, g*4 + rr);
      #pragma unroll
      for (int ni=0;ni<8;++ni){
        f32x4 t = o[ni];
        t[0]*=a4[0]; t[1]*=a4[1]; t[2]*=a4[2]; t[3]*=a4[3];
        o[ni] = t;
      }
    }
    float ps;
    {
      f32x4 s4;
      #pragma unroll
      for (int fj=0;fj<4;++fj)
        #pragma unroll
        for (int rr=0;rr<4;++rr)
          sf[fj][rr] = exp2f(sf[fj][rr] - m_r);
      #pragma unroll
      for (int rr=0;rr<4;++rr)
        s4[rr] = (sf[0][rr] + sf[1][rr]) + (sf[2][rr] + sf[3][rr]);
      ps = (s4[0] + s4[1]) + (s4[2] + s4[3]);
      ps += __shfl_xor(ps, 16);
      ps += __shfl_xor(ps, 32);
    }
    l_r += ps;
    // P -> Ps, packed 4 bf16 per b64 store (lane holds q=c, kv=fj*16+g*4+rr)
    #pragma unroll
    for (int fj=0;fj<4;++fj){
      short4 pk;
      pk.x = f2bf(sf[fj][0]); pk.y = f2bf(sf[fj][1]);
      pk.z = f2bf(sf[fj][2]); pk.w = f2bf(sf[fj][3]);
      *(short4*)&Ps[w][c][fj*16 + g*4] = pk;
    }
    __builtin_amdgcn_s_setprio(1);
    #pragma unroll
    for (int ks=0;ks<2;++ks){
      bf16x8 pa = *(const bf16x8*)&Ps[w][c][ks*32 + g*8];
      #pragma unroll
      for (int ni=0;ni<8;++ni){
        int d = ni*16 + c;
        bf16x8 vb = *(const bf16x8*)&Vs[buf][d*64 + (((ks*4+g) ^ (c&7))*8)];
        o[ni] = __builtin_amdgcn_mfma_f32_16x16x32_bf16(pa, vb, o[ni], 0,0,0);
      }
    }
    __builtin_amdgcn_s_setprio(0);
    __syncthreads();
    buf ^= 1;
  }
  int b = bh >> 5, h = bh & 31;
  float inv = 1.0f / l_r;
  float inv4[4];
  #pragma unroll
  for (int rr=0;rr<4;++rr) inv4[rr] = __shfl(inv, g*4 + rr);
  #pragma unroll
  for (int rr=0;rr<4;++rr){
    int s = qw + g*4 + rr;
    #pragma unroll
    for (int ni=0;ni<8;++ni){
      int d = ni*16 + c;
      attn[((size_t)(b*SEQ + s))*HID + h*HDIM + d] = f2bf(o[ni][rr] * inv4[rr]);
    }
  }
}

extern "C" void kernel_launch(void* const* d_in, const int* in_sizes, int n_in,
                              void* d_out, int out_size, void* d_ws, size_t ws_size,
                              hipStream_t stream){
  const float* hs   = (const float*)d_in[0];
  const int*   pos  = (const int*)d_in[1];
  const float* wqkv = (const float*)d_in[2];
  const float* wo   = (const float*)d_in[3];
  float* out = (float*)d_out;
  char* ws = (char*)d_ws;
  size_t off = 0;
  auto alloc = [&](size_t bytes){ void* p = ws + off; off += (bytes + 255) & ~(size_t)255; return p; };
  short* hsb   = (short*)alloc((size_t)MROWS*HID*2);
  short* wqkvb = (short*)alloc((size_t)3*HID*HID*2);
  short* wob   = (short*)alloc((size_t)HID*HID*2);
  short* Qb    = (short*)alloc((size_t)BH*SEQ*HDIM*2);
  short* Kb    = (short*)alloc((size_t)BH*SEQ*HDIM*2);
  short* Vb    = (short*)alloc((size_t)BH*SEQ*HDIM*2);
  short* Vt    = (short*)alloc((size_t)BH*SEQ*HDIM*2);
  short* attn  = (short*)alloc((size_t)MROWS*HID*2);
  float* tab   = (float*)alloc((size_t)SEQ*64*2*4);
  (void)ws_size; (void)in_sizes; (void)n_in; (void)out_size;

  cvt3_bf16<<<2048,256,0,stream>>>(hs, hsb, MROWS*HID/4,
                                   wqkv, wqkvb, 3*HID*HID/4,
                                   wo, wob, HID*HID/4);
  rope_table_k<<<(SEQ*64+255)/256,256,0,stream>>>(pos, tab);
  gemm8r<0><<<dim3(48,16),512,0,stream>>>(hsb, wqkvb, Qb, Kb, Vb, nullptr);
  rope_apply_k<<<(BH*SEQ*8+255)/256,256,0,stream>>>(Qb, Kb, tab);
  transpose_v_k<<<dim3(SEQ/32, HDIM/32, BH),256,0,stream>>>(Vb, Vt);
  flash_attn_k<<<dim3(SEQ/64, BH),256,0,stream>>>(Qb, Kb, Vt, attn);
  gemm8r<1><<<dim3(16,16),512,0,stream>>>(attn, wob, nullptr, nullptr, nullptr, out);
}

// Round 14
// 761.106 us; speedup vs baseline: 1.0685x; 1.0309x over previous
//
#include <hip/hip_runtime.h>
#include <hip/hip_bf16.h>

#define BATCH 2
#define SEQ 2048
#define HID 4096
#define NHEAD 32
#define HDIM 128
#define BH (BATCH*NHEAD)   /* 64 */
#define MROWS (BATCH*SEQ)  /* 4096 */
#define SC2 0.1275187963f   /* (1/sqrt(128)) * log2(e), folded into Q in rope */

typedef __attribute__((ext_vector_type(8))) short bf16x8;
typedef __attribute__((ext_vector_type(4))) float f32x4;

__device__ __forceinline__ float bf2f(short x){
  union { float f; unsigned u; } v; v.u = ((unsigned)(unsigned short)x) << 16; return v.f;
}
__device__ __forceinline__ short f2bf(float f){
  union { float f; unsigned u; } v; v.f = f;
  unsigned r = v.u + 0x7fffu + ((v.u >> 16) & 1u);
  return (short)(r >> 16);
}
__device__ __forceinline__ void gload_lds16(const void* g, void* l){
  __builtin_amdgcn_global_load_lds(
    (const __attribute__((address_space(1))) void*)g,
    (__attribute__((address_space(3))) void*)l, 16, 0, 0);
}

// ---------------- fused f32 -> bf16 convert (3 tensors) ----------------
__global__ void cvt3_bf16(const float* __restrict__ a, short* __restrict__ ao, int na4,
                          const float* __restrict__ b, short* __restrict__ bo, int nb4,
                          const float* __restrict__ cc, short* __restrict__ co, int nc4){
  int i = blockIdx.x*blockDim.x + threadIdx.x;
  int stride = gridDim.x*blockDim.x;
  int tot = na4 + nb4 + nc4;
  for (; i < tot; i += stride){
    const float* src; short* dst; int k = i;
    if (k < na4){ src=a; dst=ao; }
    else if (k < na4+nb4){ k -= na4; src=b; dst=bo; }
    else { k -= na4+nb4; src=cc; dst=co; }
    float4 v = ((const float4*)src)[k];
    short4 o;
    o.x = f2bf(v.x); o.y = f2bf(v.y); o.z = f2bf(v.z); o.w = f2bf(v.w);
    ((short4*)dst)[k] = o;
  }
}

// ---------------- RoPE cos/sin table ----------------
__global__ void rope_table_k(const int* __restrict__ pos, float* __restrict__ tab){
  int idx = blockIdx.x*blockDim.x + threadIdx.x;
  if (idx >= SEQ*64) return;
  int s = idx >> 6, d = idx & 63;
  float p = (float)pos[s];
  float inv = exp2f(-(float)d * (13.287712379549449f/64.0f)); // 10000^(-d/64)
  float ang = p * inv;
  tab[2*idx]   = cosf(ang);
  tab[2*idx+1] = sinf(ang);
}

// ===== 256x256 8-phase GEMM, minimal LDS reads (24 b128/K-tile), vmcnt(6/8) =====
// (round-5 known-good: 395us QKV, MfmaUtil 45.6, 0 bank conflicts, no spill.
//  Verified local optimum: r4 collapse, r7 spill, r9 {8,0,8,8} -7%, r12 evened -4%.)
template<int W>
__device__ __forceinline__ void stage_half(const short* __restrict__ gsrc, int ldg,
                                           short* lds, int tid, int h){
  #pragma unroll
  for (int li=0; li<2; ++li){
    int e16 = li*512 + tid;
    int rs = e16 >> 3, ck = e16 & 7;
    int r = ((rs/W)*2 + h)*W + (rs%W);
    gload_lds16(gsrc + (size_t)r*ldg + ((ck ^ (r&7))<<3),
                lds + r*64 + ck*8);
  }
}

__device__ __forceinline__ void read_ahalf(const short* Asb, int wr, int c, int g,
                                           int Mh, bf16x8 (&afr)[4][2]){
  #pragma unroll
  for (int mi=0; mi<4; ++mi){
    int row = wr*128 + (Mh*4+mi)*16 + c;
    const char* bp = (const char*)Asb + row*128;
    #pragma unroll
    for (int kk=0; kk<2; ++kk)
      afr[mi][kk] = *(const bf16x8*)(bp + ((kk*64 + g*16) ^ ((row&7)<<4)));
  }
}
__device__ __forceinline__ void read_bhalf(const short* Bsb, int wc, int c, int g,
                                           int Nh, bf16x8 (&bfr)[2][2]){
  #pragma unroll
  for (int ni=0; ni<2; ++ni){
    int row = wc*64 + (Nh*2+ni)*16 + c;
    const char* bp = (const char*)Bsb + row*128;
    #pragma unroll
    for (int kk=0; kk<2; ++kk)
      bfr[ni][kk] = *(const bf16x8*)(bp + ((kk*64 + g*16) ^ ((row&7)<<4)));
  }
}
template<int MH, int NHH>
__device__ __forceinline__ void mma_q(bf16x8 (&afr)[4][2], bf16x8 (&bfr)[2][2],
                                      f32x4 (&acc)[8][4]){
  #pragma unroll
  for (int kk=0; kk<2; ++kk)
    #pragma unroll
    for (int mi=0; mi<4; ++mi)
      #pragma unroll
      for (int ni=0; ni<2; ++ni)
        acc[MH*4+mi][NHH*2+ni] = __builtin_amdgcn_mfma_f32_16x16x32_bf16(
            afr[mi][kk], bfr[ni][kk], acc[MH*4+mi][NHH*2+ni], 0,0,0);
}

#define BAR()  asm volatile("s_barrier" ::: "memory")
#define LGK0() asm volatile("s_waitcnt lgkmcnt(0)" ::: "memory")
#define VMC6() asm volatile("s_waitcnt vmcnt(6)" ::: "memory")
#define VMC8() asm volatile("s_waitcnt vmcnt(8)" ::: "memory")
#define VMC0() asm volatile("s_waitcnt vmcnt(0)" ::: "memory")
#define SP1()  __builtin_amdgcn_s_setprio(1)
#define SP0()  __builtin_amdgcn_s_setprio(0)

// MODE 0: QKV proj -> clip +-8 -> scatter bf16 into Q/K/V [BH][S][HD]
// MODE 1: O proj -> f32 row-major out
template<int MODE>
__global__ __launch_bounds__(512, 2) void gemm8r(
    const short* __restrict__ A, const short* __restrict__ Bw,
    short* __restrict__ Qb, short* __restrict__ Kb, short* __restrict__ Vb,
    float* __restrict__ Of){
  __shared__ __align__(16) short As[2][256*64];
  __shared__ __align__(16) short Bs[2][256*64];
  const int K = HID;
  int tid = threadIdx.x, lane = tid & 63, w = tid >> 6;
  int wr = w >> 2, wc = w & 3, g = lane >> 4, c = lane & 15;
  int gx = gridDim.x;
  int nwg = gx * gridDim.y;
  int bid = blockIdx.y*gx + blockIdx.x;
  int cpx = nwg >> 3;
  int swz = (bid & 7)*cpx + (bid >> 3);
  int m0 = (swz / gx) * 256, n0 = (swz % gx) * 256;

  const short* Abase = A  + (size_t)m0*K;
  const short* Bbase = Bw + (size_t)n0*K;
  auto stageA = [&](int buf, int kt, int h){
    stage_half<64>(Abase + kt*64, K, &As[buf][0], tid, h);
  };
  auto stageB = [&](int buf, int kt, int h){
    stage_half<32>(Bbase + kt*64, K, &Bs[buf][0], tid, h);
  };

  f32x4 acc[8][4];
  f32x4 zero = {0.f,0.f,0.f,0.f};
  #pragma unroll
  for (int i=0;i<8;++i)
    #pragma unroll
    for (int j=0;j<4;++j) acc[i][j] = zero;
  bf16x8 afr[4][2], bfr0[2][2], bfr1[2][2];

  stageB(0,0,0); stageB(0,0,1); stageA(0,0,0); stageA(0,0,1);
  stageB(1,1,0); stageB(1,1,1); stageA(1,1,0); stageA(1,1,1);
  VMC8();
  BAR();

  const int NITER = K/128;  // 32 iterations, 2 K-tiles each
  for (int i = 0; i < NITER-1; ++i){
    int t2 = 2*i+2, t3 = 2*i+3;
    read_ahalf(&As[0][0], wr,c,g, 0, afr);
    read_bhalf(&Bs[0][0], wc,c,g, 0, bfr0);
    BAR(); LGK0(); SP1(); mma_q<0,0>(afr,bfr0,acc); SP0(); BAR();
    read_bhalf(&Bs[0][0], wc,c,g, 1, bfr1);
    stageB(0, t2, 0);
    BAR(); LGK0(); SP1(); mma_q<0,1>(afr,bfr1,acc); SP0(); BAR();
    read_ahalf(&As[0][0], wr,c,g, 1, afr);
    stageB(0, t2, 1); stageA(0, t2, 0);
    BAR(); LGK0(); SP1(); mma_q<1,1>(afr,bfr1,acc); SP0(); BAR();
    BAR(); LGK0(); SP1(); mma_q<1,0>(afr,bfr0,acc); SP0(); VMC6(); BAR();
    read_ahalf(&As[1][0], wr,c,g, 0, afr);
    read_bhalf(&Bs[1][0], wc,c,g, 0, bfr0);
    stageA(0, t2, 1);
    BAR(); LGK0(); SP1(); mma_q<0,0>(afr,bfr0,acc); SP0(); BAR();
    read_bhalf(&Bs[1][0], wc,c,g, 1, bfr1);
    stageB(1, t3, 0);
    BAR(); LGK0(); SP1(); mma_q<0,1>(afr,bfr1,acc); SP0(); BAR();
    read_ahalf(&As[1][0], wr,c,g, 1, afr);
    stageB(1, t3, 1); stageA(1, t3, 0);
    BAR(); LGK0(); SP1(); mma_q<1,1>(afr,bfr1,acc); SP0(); BAR();
    stageA(1, t3, 1);
    BAR(); LGK0(); SP1(); mma_q<1,0>(afr,bfr0,acc); SP0(); VMC8(); BAR();
  }
  {
    read_ahalf(&As[0][0], wr,c,g, 0, afr);
    read_bhalf(&Bs[0][0], wc,c,g, 0, bfr0);
    BAR(); LGK0(); SP1(); mma_q<0,0>(afr,bfr0,acc); SP0(); BAR();
    read_bhalf(&Bs[0][0], wc,c,g, 1, bfr1);
    BAR(); LGK0(); SP1(); mma_q<0,1>(afr,bfr1,acc); SP0(); BAR();
    read_ahalf(&As[0][0], wr,c,g, 1, afr);
    BAR(); LGK0(); SP1(); mma_q<1,1>(afr,bfr1,acc); SP0(); BAR();
    BAR(); LGK0(); SP1(); mma_q<1,0>(afr,bfr0,acc); SP0(); VMC0(); BAR();
    read_ahalf(&As[1][0], wr,c,g, 0, afr);
    read_bhalf(&Bs[1][0], wc,c,g, 0, bfr0);
    BAR(); LGK0(); SP1(); mma_q<0,0>(afr,bfr0,acc); SP0(); BAR();
    read_bhalf(&Bs[1][0], wc,c,g, 1, bfr1);
    BAR(); LGK0(); SP1(); mma_q<0,1>(afr,bfr1,acc); SP0(); BAR();
    read_ahalf(&As[1][0], wr,c,g, 1, afr);
    BAR(); LGK0(); SP1(); mma_q<1,1>(afr,bfr1,acc); SP0(); BAR();
    BAR(); LGK0(); SP1(); mma_q<1,0>(afr,bfr0,acc); SP0(); BAR();
  }

  #pragma unroll
  for (int fa=0; fa<8; ++fa){
    #pragma unroll
    for (int fb=0; fb<4; ++fb){
      f32x4 v = acc[fa][fb];
      #pragma unroll
      for (int rr=0; rr<4; ++rr){
        int row = m0 + wr*128 + fa*16 + g*4 + rr;
        int col = n0 + wc*64  + fb*16 + c;
        float x = v[rr];
        if (MODE == 0){
          x = fminf(fmaxf(x, -8.0f), 8.0f);
          int sel = col >> 12, wi = col & 4095;
          int head = wi >> 7, d = wi & 127;
          int b = row >> 11, s = row & 2047;
          size_t off = ((size_t)(b*NHEAD + head)*SEQ + s)*HDIM + d;
          short* dst = (sel == 0) ? Qb : (sel == 1) ? Kb : Vb;
          dst[off] = f2bf(x);
        } else {
          Of[(size_t)row*HID + col] = x;
        }
      }
    }
  }
}

// ---- RoPE in place on Q and K, vectorized; Q gets *SC2 (scale+log2e fold) ----
__global__ void rope_apply_k(short* __restrict__ Qb, short* __restrict__ Kb,
                             const float* __restrict__ tab){
  int idx = blockIdx.x*blockDim.x + threadIdx.x;
  if (idx >= BH*SEQ*8) return;
  int t = idx & 7;
  int s = (idx >> 3) & (SEQ-1);
  int bh = idx >> 14;
  size_t base = ((size_t)bh*SEQ + s)*HDIM + t*8;
  const float* tb = tab + 2*(s*64 + t*8);
  bf16x8 q1 = *(bf16x8*)(Qb+base), q2 = *(bf16x8*)(Qb+base+64);
  bf16x8 k1 = *(bf16x8*)(Kb+base), k2 = *(bf16x8*)(Kb+base+64);
  bf16x8 o1, o2, p1, p2;
  #pragma unroll
  for (int u=0;u<8;++u){
    float cs = tb[2*u], sn = tb[2*u+1];
    float a = bf2f(q1[u]), b = bf2f(q2[u]);
    o1[u] = f2bf((a*cs - b*sn)*SC2); o2[u] = f2bf((b*cs + a*sn)*SC2);
    a = bf2f(k1[u]); b = bf2f(k2[u]);
    p1[u] = f2bf(a*cs - b*sn); p2[u] = f2bf(b*cs + a*sn);
  }
  *(bf16x8*)(Qb+base)    = o1; *(bf16x8*)(Qb+base+64) = o2;
  *(bf16x8*)(Kb+base)    = p1; *(bf16x8*)(Kb+base+64) = p2;
}

// ---------------- V transpose: [BH][S][HD] -> Vt [BH][HD][S] ----------------
__global__ void transpose_v_k(const short* __restrict__ V, short* __restrict__ Vt){
  __shared__ short t[32][33];
  int bh = blockIdx.z;
  int s0 = blockIdx.x*32, d0 = blockIdx.y*32;
  int tx = threadIdx.x & 31, ty = threadIdx.x >> 5;  // 32 x 8
  const short* src = V + ((size_t)bh*SEQ + s0)*HDIM + d0;
  #pragma unroll
  for (int i=ty;i<32;i+=8) t[i][tx] = src[(size_t)i*HDIM + tx];
  __syncthreads();
  short* dst = Vt + ((size_t)bh*HDIM + d0)*SEQ + s0;
  #pragma unroll
  for (int i=ty;i<32;i+=8) dst[(size_t)i*SEQ + tx] = t[tx][i];
}

// ======== Flash attention, causal, QBLK=128 / KVBLK=64, 8 waves, swapped QK^T ====
// Lane (g,c) holds S[q=c][kv=fj*16+g*4+rr]; row softmax = in-reg tree + 2 shfls.
// Stage traffic halves vs QBLK=64 (272 vs 528 tiles/bh). Heavy-first dispatch.
// Ps[8][16][64] XOR-swizzled (col ^ ((c&7)<<3)): PV b128 read = GEMM-proven pattern.
// LDS = 80KB exactly -> 2 blocks/CU (4 waves/SIMD).
__global__ __launch_bounds__(512, 4) void flash_attn_k(
    const short* __restrict__ Qb, const short* __restrict__ Kb,
    const short* __restrict__ Vt, short* __restrict__ attn){
  __shared__ short Ks[2][64*128];   // 32 KB, chunk-swizzled
  __shared__ short Vs[2][128*64];   // 32 KB, chunk-swizzled
  __shared__ short Ps[8][16][64];   // 16 KB, XOR-swizzled
  int tid = threadIdx.x, lane = tid & 63, w = tid >> 6;
  int g = lane >> 4, c = lane & 15;
  // XCD-clustered (16 jq-blocks of one bh per XCD), heavy-first
  int flat = blockIdx.x;
  int xcd = flat & 7, idx = flat >> 3;
  int bh = xcd + 8*(idx >> 4);
  int jq = 15 - (idx & 15);
  int qw = jq*128 + w*16;           // this wave's 16 q-rows
  bf16x8 qf[4];
  #pragma unroll
  for (int ks=0;ks<4;++ks)
    qf[ks] = *(const bf16x8*)(Qb + ((size_t)bh*SEQ + qw + c)*HDIM + ks*32 + g*8);
  f32x4 o[8];
  f32x4 zero = {0.f,0.f,0.f,0.f};
  #pragma unroll
  for (int i=0;i<8;++i) o[i] = zero;
  float m_r = -1e30f;   // running max for q-row = qw + c
  float l_r = 0.f;

  auto stage = [&](int j, int b){
    int kv0 = j*64;
    #pragma unroll
    for (int i=0;i<2;++i){
      int e = i*512 + tid;
      int kr = e >> 4, kc = e & 15;
      gload_lds16(Kb + ((size_t)bh*SEQ + kv0 + kr)*HDIM + (size_t)((kc ^ (kr&7))*8),
                  &Ks[b][kr*128 + kc*8]);
      int vr = e >> 3, vc = e & 7;
      gload_lds16(Vt + ((size_t)bh*HDIM + vr)*SEQ + kv0 + (size_t)((vc ^ (vr&7))*8),
                  &Vs[b][vr*64 + vc*8]);
    }
  };

  const int jmaxb = 2*jq + 1;       // block's last KV tile
  const int jmaxw = qw >> 6;        // this wave's diagonal tile (wave-uniform)

  stage(0, 0);
  __syncthreads();
  int buf = 0;
  for (int j=0; j<=jmaxb; ++j){
    if (j < jmaxb) stage(j+1, buf^1);
    if (j <= jmaxw){
      int kv0 = j*64;
      f32x4 sf[4];
      #pragma unroll
      for (int fj=0;fj<4;++fj) sf[fj] = zero;
      __builtin_amdgcn_s_setprio(1);
      #pragma unroll
      for (int ks=0;ks<4;++ks){
        #pragma unroll
        for (int fj=0;fj<4;++fj){
          int kvrow = fj*16 + c;
          bf16x8 kb = *(const bf16x8*)&Ks[buf][kvrow*128 + (((ks*4+g) ^ (c&7))*8)];
          sf[fj] = __builtin_amdgcn_mfma_f32_16x16x32_bf16(kb, qf[ks], sf[fj], 0,0,0);
        }
      }
      __builtin_amdgcn_s_setprio(0);
      if (j == jmaxw){
        int q = qw + c;
        #pragma unroll
        for (int fj=0;fj<4;++fj)
          #pragma unroll
          for (int rr=0;rr<4;++rr)
            if ((kv0 + fj*16 + g*4 + rr) > q) sf[fj][rr] = -1e30f;
      }
      f32x4 t4;
      #pragma unroll
      for (int rr=0;rr<4;++rr)
        t4[rr] = fmaxf(fmaxf(sf[0][rr], sf[1][rr]), fmaxf(sf[2][rr], sf[3][rr]));
      float rmax = fmaxf(fmaxf(t4[0], t4[1]), fmaxf(t4[2], t4[3]));
      rmax = fmaxf(rmax, __shfl_xor(rmax, 16));
      rmax = fmaxf(rmax, __shfl_xor(rmax, 32));
      if (__any(rmax > m_r + 8.0f)){
        float mnew = fmaxf(m_r, rmax);
        float alpha = exp2f(m_r - mnew);
        m_r = mnew;
        l_r *= alpha;
        float a4[4];
        #pragma unroll
        for (int rr=0;rr<4;++rr) a4[rr] = __shfl(alpha, g*4 + rr);
        #pragma unroll
        for (int ni=0;ni<8;++ni){
          f32x4 t = o[ni];
          t[0]*=a4[0]; t[1]*=a4[1]; t[2]*=a4[2]; t[3]*=a4[3];
          o[ni] = t;
        }
      }
      float ps;
      {
        f32x4 s4;
        #pragma unroll
        for (int fj=0;fj<4;++fj)
          #pragma unroll
          for (int rr=0;rr<4;++rr)
            sf[fj][rr] = exp2f(sf[fj][rr] - m_r);
        #pragma unroll
        for (int rr=0;rr<4;++rr)
          s4[rr] = (sf[0][rr] + sf[1][rr]) + (sf[2][rr] + sf[3][rr]);
        ps = (s4[0] + s4[1]) + (s4[2] + s4[3]);
        ps += __shfl_xor(ps, 16);
        ps += __shfl_xor(ps, 32);
      }
      l_r += ps;
      // P -> Ps: lane holds q=c, kv=fj*16+g*4+rr; swizzled b64 store
      #pragma unroll
      for (int fj=0;fj<4;++fj){
        short4 pk;
        pk.x = f2bf(sf[fj][0]); pk.y = f2bf(sf[fj][1]);
        pk.z = f2bf(sf[fj][2]); pk.w = f2bf(sf[fj][3]);
        *(short4*)&Ps[w][c][(fj*16 + g*4) ^ ((c&7)<<3)] = pk;
      }
      __builtin_amdgcn_s_setprio(1);
      #pragma unroll
      for (int ks=0;ks<2;++ks){
        bf16x8 pa = *(const bf16x8*)&Ps[w][c][(ks*32 + g*8) ^ ((c&7)<<3)];
        #pragma unroll
        for (int ni=0;ni<8;++ni){
          int d = ni*16 + c;
          bf16x8 vb = *(const bf16x8*)&Vs[buf][d*64 + (((ks*4+g) ^ (c&7))*8)];
          o[ni] = __builtin_amdgcn_mfma_f32_16x16x32_bf16(pa, vb, o[ni], 0,0,0);
        }
      }
      __builtin_amdgcn_s_setprio(0);
    }
    __syncthreads();   // drains stage(j+1) vmcnt + Ks/Vs reuse
    buf ^= 1;
  }
  int b = bh >> 5, h = bh & 31;
  float inv = 1.0f / l_r;
  float inv4[4];
  #pragma unroll
  for (int rr=0;rr<4;++rr) inv4[rr] = __shfl(inv, g*4 + rr);
  #pragma unroll
  for (int rr=0;rr<4;++rr){
    int s = qw + g*4 + rr;
    #pragma unroll
    for (int ni=0;ni<8;++ni){
      int d = ni*16 + c;
      attn[((size_t)(b*SEQ + s))*HID + h*HDIM + d] = f2bf(o[ni][rr] * inv4[rr]);
    }
  }
}

extern "C" void kernel_launch(void* const* d_in, const int* in_sizes, int n_in,
                              void* d_out, int out_size, void* d_ws, size_t ws_size,
                              hipStream_t stream){
  const float* hs   = (const float*)d_in[0];
  const int*   pos  = (const int*)d_in[1];
  const float* wqkv = (const float*)d_in[2];
  const float* wo   = (const float*)d_in[3];
  float* out = (float*)d_out;
  char* ws = (char*)d_ws;
  size_t off = 0;
  auto alloc = [&](size_t bytes){ void* p = ws + off; off += (bytes + 255) & ~(size_t)255; return p; };
  short* hsb   = (short*)alloc((size_t)MROWS*HID*2);
  short* wqkvb = (short*)alloc((size_t)3*HID*HID*2);
  short* wob   = (short*)alloc((size_t)HID*HID*2);
  short* Qb    = (short*)alloc((size_t)BH*SEQ*HDIM*2);
  short* Kb    = (short*)alloc((size_t)BH*SEQ*HDIM*2);
  short* Vb    = (short*)alloc((size_t)BH*SEQ*HDIM*2);
  short* Vt    = (short*)alloc((size_t)BH*SEQ*HDIM*2);
  short* attn  = (short*)alloc((size_t)MROWS*HID*2);
  float* tab   = (float*)alloc((size_t)SEQ*64*2*4);
  (void)ws_size; (void)in_sizes; (void)n_in; (void)out_size;

  cvt3_bf16<<<2048,256,0,stream>>>(hs, hsb, MROWS*HID/4,
                                   wqkv, wqkvb, 3*HID*HID/4,
                                   wo, wob, HID*HID/4);
  rope_table_k<<<(SEQ*64+255)/256,256,0,stream>>>(pos, tab);
  gemm8r<0><<<dim3(48,16),512,0,stream>>>(hsb, wqkvb, Qb, Kb, Vb, nullptr);
  rope_apply_k<<<(BH*SEQ*8+255)/256,256,0,stream>>>(Qb, Kb, tab);
  transpose_v_k<<<dim3(SEQ/32, HDIM/32, BH),256,0,stream>>>(Vb, Vt);
  flash_attn_k<<<dim3(BH*16),512,0,stream>>>(Qb, Kb, Vt, attn);
  gemm8r<1><<<dim3(16,16),512,0,stream>>>(attn, wob, nullptr, nullptr, nullptr, out);
}

// Round 15
// 745.594 us; speedup vs baseline: 1.0908x; 1.0208x over previous
//
#include <hip/hip_runtime.h>
#include <hip/hip_bf16.h>

#define BATCH 2
#define SEQ 2048
#define HID 4096
#define NHEAD 32
#define HDIM 128
#define BH (BATCH*NHEAD)   /* 64 */
#define MROWS (BATCH*SEQ)  /* 4096 */
#define SC2 0.1275187963f   /* (1/sqrt(128)) * log2(e), folded into Q in rope */

typedef __attribute__((ext_vector_type(8))) short bf16x8;
typedef __attribute__((ext_vector_type(4))) float f32x4;

__device__ __forceinline__ float bf2f(short x){
  union { float f; unsigned u; } v; v.u = ((unsigned)(unsigned short)x) << 16; return v.f;
}
__device__ __forceinline__ short f2bf(float f){
  __hip_bfloat16 h = __float2bfloat16(f);   // native RNE convert (1 inst)
  return *(short*)&h;
}
__device__ __forceinline__ void gload_lds16(const void* g, void* l){
  __builtin_amdgcn_global_load_lds(
    (const __attribute__((address_space(1))) void*)g,
    (__attribute__((address_space(3))) void*)l, 16, 0, 0);
}

// ---------------- fused f32 -> bf16 convert (3 tensors) ----------------
__global__ void cvt3_bf16(const float* __restrict__ a, short* __restrict__ ao, int na4,
                          const float* __restrict__ b, short* __restrict__ bo, int nb4,
                          const float* __restrict__ cc, short* __restrict__ co, int nc4){
  int i = blockIdx.x*blockDim.x + threadIdx.x;
  int stride = gridDim.x*blockDim.x;
  int tot = na4 + nb4 + nc4;
  for (; i < tot; i += stride){
    const float* src; short* dst; int k = i;
    if (k < na4){ src=a; dst=ao; }
    else if (k < na4+nb4){ k -= na4; src=b; dst=bo; }
    else { k -= na4+nb4; src=cc; dst=co; }
    float4 v = ((const float4*)src)[k];
    short4 o;
    o.x = f2bf(v.x); o.y = f2bf(v.y); o.z = f2bf(v.z); o.w = f2bf(v.w);
    ((short4*)dst)[k] = o;
  }
}

// ---------------- RoPE cos/sin table ----------------
__global__ void rope_table_k(const int* __restrict__ pos, float* __restrict__ tab){
  int idx = blockIdx.x*blockDim.x + threadIdx.x;
  if (idx >= SEQ*64) return;
  int s = idx >> 6, d = idx & 63;
  float p = (float)pos[s];
  float inv = exp2f(-(float)d * (13.287712379549449f/64.0f)); // 10000^(-d/64)
  float ang = p * inv;
  tab[2*idx]   = cosf(ang);
  tab[2*idx+1] = sinf(ang);
}

// ===== 256x256 8-phase GEMM, minimal LDS reads (24 b128/K-tile), vmcnt(6/8) =====
// (round-5 known-good: 395us QKV, MfmaUtil 45.6, 0 bank conflicts, no spill.
//  Verified local optimum: r4 collapse, r7 spill, r9 {8,0,8,8} -7%, r12 evened -4%.)
template<int W>
__device__ __forceinline__ void stage_half(const short* __restrict__ gsrc, int ldg,
                                           short* lds, int tid, int h){
  #pragma unroll
  for (int li=0; li<2; ++li){
    int e16 = li*512 + tid;
    int rs = e16 >> 3, ck = e16 & 7;
    int r = ((rs/W)*2 + h)*W + (rs%W);
    gload_lds16(gsrc + (size_t)r*ldg + ((ck ^ (r&7))<<3),
                lds + r*64 + ck*8);
  }
}

__device__ __forceinline__ void read_ahalf(const short* Asb, int wr, int c, int g,
                                           int Mh, bf16x8 (&afr)[4][2]){
  #pragma unroll
  for (int mi=0; mi<4; ++mi){
    int row = wr*128 + (Mh*4+mi)*16 + c;
    const char* bp = (const char*)Asb + row*128;
    #pragma unroll
    for (int kk=0; kk<2; ++kk)
      afr[mi][kk] = *(const bf16x8*)(bp + ((kk*64 + g*16) ^ ((row&7)<<4)));
  }
}
__device__ __forceinline__ void read_bhalf(const short* Bsb, int wc, int c, int g,
                                           int Nh, bf16x8 (&bfr)[2][2]){
  #pragma unroll
  for (int ni=0; ni<2; ++ni){
    int row = wc*64 + (Nh*2+ni)*16 + c;
    const char* bp = (const char*)Bsb + row*128;
    #pragma unroll
    for (int kk=0; kk<2; ++kk)
      bfr[ni][kk] = *(const bf16x8*)(bp + ((kk*64 + g*16) ^ ((row&7)<<4)));
  }
}
template<int MH, int NHH>
__device__ __forceinline__ void mma_q(bf16x8 (&afr)[4][2], bf16x8 (&bfr)[2][2],
                                      f32x4 (&acc)[8][4]){
  #pragma unroll
  for (int kk=0; kk<2; ++kk)
    #pragma unroll
    for (int mi=0; mi<4; ++mi)
      #pragma unroll
      for (int ni=0; ni<2; ++ni)
        acc[MH*4+mi][NHH*2+ni] = __builtin_amdgcn_mfma_f32_16x16x32_bf16(
            afr[mi][kk], bfr[ni][kk], acc[MH*4+mi][NHH*2+ni], 0,0,0);
}

#define BAR()  asm volatile("s_barrier" ::: "memory")
#define LGK0() asm volatile("s_waitcnt lgkmcnt(0)" ::: "memory")
#define VMC6() asm volatile("s_waitcnt vmcnt(6)" ::: "memory")
#define VMC8() asm volatile("s_waitcnt vmcnt(8)" ::: "memory")
#define VMC0() asm volatile("s_waitcnt vmcnt(0)" ::: "memory")
#define SP1()  __builtin_amdgcn_s_setprio(1)
#define SP0()  __builtin_amdgcn_s_setprio(0)

// MODE 0: QKV proj -> clip +-8 -> scatter bf16 into Q/K/V [BH][S][HD]
// MODE 1: O proj -> f32 row-major out
template<int MODE>
__global__ __launch_bounds__(512, 2) void gemm8r(
    const short* __restrict__ A, const short* __restrict__ Bw,
    short* __restrict__ Qb, short* __restrict__ Kb, short* __restrict__ Vb,
    float* __restrict__ Of){
  __shared__ __align__(16) short As[2][256*64];
  __shared__ __align__(16) short Bs[2][256*64];
  const int K = HID;
  int tid = threadIdx.x, lane = tid & 63, w = tid >> 6;
  int wr = w >> 2, wc = w & 3, g = lane >> 4, c = lane & 15;
  int gx = gridDim.x;
  int nwg = gx * gridDim.y;
  int bid = blockIdx.y*gx + blockIdx.x;
  int cpx = nwg >> 3;
  int swz = (bid & 7)*cpx + (bid >> 3);
  int m0 = (swz / gx) * 256, n0 = (swz % gx) * 256;

  const short* Abase = A  + (size_t)m0*K;
  const short* Bbase = Bw + (size_t)n0*K;
  auto stageA = [&](int buf, int kt, int h){
    stage_half<64>(Abase + kt*64, K, &As[buf][0], tid, h);
  };
  auto stageB = [&](int buf, int kt, int h){
    stage_half<32>(Bbase + kt*64, K, &Bs[buf][0], tid, h);
  };

  f32x4 acc[8][4];
  f32x4 zero = {0.f,0.f,0.f,0.f};
  #pragma unroll
  for (int i=0;i<8;++i)
    #pragma unroll
    for (int j=0;j<4;++j) acc[i][j] = zero;
  bf16x8 afr[4][2], bfr0[2][2], bfr1[2][2];

  stageB(0,0,0); stageB(0,0,1); stageA(0,0,0); stageA(0,0,1);
  stageB(1,1,0); stageB(1,1,1); stageA(1,1,0); stageA(1,1,1);
  VMC8();
  BAR();

  const int NITER = K/128;  // 32 iterations, 2 K-tiles each
  for (int i = 0; i < NITER-1; ++i){
    int t2 = 2*i+2, t3 = 2*i+3;
    read_ahalf(&As[0][0], wr,c,g, 0, afr);
    read_bhalf(&Bs[0][0], wc,c,g, 0, bfr0);
    BAR(); LGK0(); SP1(); mma_q<0,0>(afr,bfr0,acc); SP0(); BAR();
    read_bhalf(&Bs[0][0], wc,c,g, 1, bfr1);
    stageB(0, t2, 0);
    BAR(); LGK0(); SP1(); mma_q<0,1>(afr,bfr1,acc); SP0(); BAR();
    read_ahalf(&As[0][0], wr,c,g, 1, afr);
    stageB(0, t2, 1); stageA(0, t2, 0);
    BAR(); LGK0(); SP1(); mma_q<1,1>(afr,bfr1,acc); SP0(); BAR();
    BAR(); LGK0(); SP1(); mma_q<1,0>(afr,bfr0,acc); SP0(); VMC6(); BAR();
    read_ahalf(&As[1][0], wr,c,g, 0, afr);
    read_bhalf(&Bs[1][0], wc,c,g, 0, bfr0);
    stageA(0, t2, 1);
    BAR(); LGK0(); SP1(); mma_q<0,0>(afr,bfr0,acc); SP0(); BAR();
    read_bhalf(&Bs[1][0], wc,c,g, 1, bfr1);
    stageB(1, t3, 0);
    BAR(); LGK0(); SP1(); mma_q<0,1>(afr,bfr1,acc); SP0(); BAR();
    read_ahalf(&As[1][0], wr,c,g, 1, afr);
    stageB(1, t3, 1); stageA(1, t3, 0);
    BAR(); LGK0(); SP1(); mma_q<1,1>(afr,bfr1,acc); SP0(); BAR();
    stageA(1, t3, 1);
    BAR(); LGK0(); SP1(); mma_q<1,0>(afr,bfr0,acc); SP0(); VMC8(); BAR();
  }
  {
    read_ahalf(&As[0][0], wr,c,g, 0, afr);
    read_bhalf(&Bs[0][0], wc,c,g, 0, bfr0);
    BAR(); LGK0(); SP1(); mma_q<0,0>(afr,bfr0,acc); SP0(); BAR();
    read_bhalf(&Bs[0][0], wc,c,g, 1, bfr1);
    BAR(); LGK0(); SP1(); mma_q<0,1>(afr,bfr1,acc); SP0(); BAR();
    read_ahalf(&As[0][0], wr,c,g, 1, afr);
    BAR(); LGK0(); SP1(); mma_q<1,1>(afr,bfr1,acc); SP0(); BAR();
    BAR(); LGK0(); SP1(); mma_q<1,0>(afr,bfr0,acc); SP0(); VMC0(); BAR();
    read_ahalf(&As[1][0], wr,c,g, 0, afr);
    read_bhalf(&Bs[1][0], wc,c,g, 0, bfr0);
    BAR(); LGK0(); SP1(); mma_q<0,0>(afr,bfr0,acc); SP0(); BAR();
    read_bhalf(&Bs[1][0], wc,c,g, 1, bfr1);
    BAR(); LGK0(); SP1(); mma_q<0,1>(afr,bfr1,acc); SP0(); BAR();
    read_ahalf(&As[1][0], wr,c,g, 1, afr);
    BAR(); LGK0(); SP1(); mma_q<1,1>(afr,bfr1,acc); SP0(); BAR();
    BAR(); LGK0(); SP1(); mma_q<1,0>(afr,bfr0,acc); SP0(); BAR();
  }

  #pragma unroll
  for (int fa=0; fa<8; ++fa){
    #pragma unroll
    for (int fb=0; fb<4; ++fb){
      f32x4 v = acc[fa][fb];
      #pragma unroll
      for (int rr=0; rr<4; ++rr){
        int row = m0 + wr*128 + fa*16 + g*4 + rr;
        int col = n0 + wc*64  + fb*16 + c;
        float x = v[rr];
        if (MODE == 0){
          x = fminf(fmaxf(x, -8.0f), 8.0f);
          int sel = col >> 12, wi = col & 4095;
          int head = wi >> 7, d = wi & 127;
          int b = row >> 11, s = row & 2047;
          size_t off = ((size_t)(b*NHEAD + head)*SEQ + s)*HDIM + d;
          short* dst = (sel == 0) ? Qb : (sel == 1) ? Kb : Vb;
          dst[off] = f2bf(x);
        } else {
          Of[(size_t)row*HID + col] = x;
        }
      }
    }
  }
}

// ---- RoPE in place on Q and K, vectorized; Q gets *SC2 (scale+log2e fold) ----
__global__ void rope_apply_k(short* __restrict__ Qb, short* __restrict__ Kb,
                             const float* __restrict__ tab){
  int idx = blockIdx.x*blockDim.x + threadIdx.x;
  if (idx >= BH*SEQ*8) return;
  int t = idx & 7;
  int s = (idx >> 3) & (SEQ-1);
  int bh = idx >> 14;
  size_t base = ((size_t)bh*SEQ + s)*HDIM + t*8;
  const float* tb = tab + 2*(s*64 + t*8);
  bf16x8 q1 = *(bf16x8*)(Qb+base), q2 = *(bf16x8*)(Qb+base+64);
  bf16x8 k1 = *(bf16x8*)(Kb+base), k2 = *(bf16x8*)(Kb+base+64);
  bf16x8 o1, o2, p1, p2;
  #pragma unroll
  for (int u=0;u<8;++u){
    float cs = tb[2*u], sn = tb[2*u+1];
    float a = bf2f(q1[u]), b = bf2f(q2[u]);
    o1[u] = f2bf((a*cs - b*sn)*SC2); o2[u] = f2bf((b*cs + a*sn)*SC2);
    a = bf2f(k1[u]); b = bf2f(k2[u]);
    p1[u] = f2bf(a*cs - b*sn); p2[u] = f2bf(b*cs + a*sn);
  }
  *(bf16x8*)(Qb+base)    = o1; *(bf16x8*)(Qb+base+64) = o2;
  *(bf16x8*)(Kb+base)    = p1; *(bf16x8*)(Kb+base+64) = p2;
}

// ---- V transpose: [BH][S][HD] -> Vt [BH][HD][S], 64x64 tiles, short4 both ways ----
__global__ void transpose_v_k(const short* __restrict__ V, short* __restrict__ Vt){
  __shared__ short t[64][68];
  int bh = blockIdx.z;
  int s0 = blockIdx.x*64, d0 = blockIdx.y*64;
  int q = threadIdx.x & 15, r4 = threadIdx.x >> 4;   // 16 quads x 16 row-groups
  const short* src = V + ((size_t)bh*SEQ + s0)*HDIM + d0;
  #pragma unroll
  for (int p=0;p<4;++p){
    int row = p*16 + r4;
    *(short4*)&t[row][q*4] = *(const short4*)&src[(size_t)row*HDIM + q*4];
  }
  __syncthreads();
  short* dst = Vt + ((size_t)bh*HDIM + d0)*SEQ + s0;
  #pragma unroll
  for (int p=0;p<4;++p){
    int drow = p*16 + r4;
    short4 v;
    v.x = t[q*4+0][drow]; v.y = t[q*4+1][drow];
    v.z = t[q*4+2][drow]; v.w = t[q*4+3][drow];
    *(short4*)&dst[(size_t)drow*SEQ + q*4] = v;
  }
}

// ======== Flash attention, causal, QBLK=128 / KVBLK=64, 8 waves, swapped QK^T ====
// Lane (g,c) holds S[q=c][kv=fj*16+g*4+rr]; row softmax = in-reg tree + 2 shfls.
// Ps[8][16][64] XOR-swizzled; LDS 80KB -> 2 blocks/CU. Heavy-first dispatch.
__global__ __launch_bounds__(512, 4) void flash_attn_k(
    const short* __restrict__ Qb, const short* __restrict__ Kb,
    const short* __restrict__ Vt, short* __restrict__ attn){
  __shared__ short Ks[2][64*128];   // 32 KB, chunk-swizzled
  __shared__ short Vs[2][128*64];   // 32 KB, chunk-swizzled
  __shared__ short Ps[8][16][64];   // 16 KB, XOR-swizzled
  int tid = threadIdx.x, lane = tid & 63, w = tid >> 6;
  int g = lane >> 4, c = lane & 15;
  int flat = blockIdx.x;
  int xcd = flat & 7, idx = flat >> 3;
  int bh = xcd + 8*(idx >> 4);
  int jq = 15 - (idx & 15);
  int qw = jq*128 + w*16;           // this wave's 16 q-rows
  bf16x8 qf[4];
  #pragma unroll
  for (int ks=0;ks<4;++ks)
    qf[ks] = *(const bf16x8*)(Qb + ((size_t)bh*SEQ + qw + c)*HDIM + ks*32 + g*8);
  f32x4 o[8];
  f32x4 zero = {0.f,0.f,0.f,0.f};
  #pragma unroll
  for (int i=0;i<8;++i) o[i] = zero;
  float m_r = -1e30f;   // running max for q-row = qw + c
  float l_r = 0.f;

  auto stage = [&](int j, int b){
    int kv0 = j*64;
    #pragma unroll
    for (int i=0;i<2;++i){
      int e = i*512 + tid;
      int kr = e >> 4, kc = e & 15;
      gload_lds16(Kb + ((size_t)bh*SEQ + kv0 + kr)*HDIM + (size_t)((kc ^ (kr&7))*8),
                  &Ks[b][kr*128 + kc*8]);
      int vr = e >> 3, vc = e & 7;
      gload_lds16(Vt + ((size_t)bh*HDIM + vr)*SEQ + kv0 + (size_t)((vc ^ (vr&7))*8),
                  &Vs[b][vr*64 + vc*8]);
    }
  };

  const int jmaxb = 2*jq + 1;       // block's last KV tile
  const int jmaxw = qw >> 6;        // this wave's diagonal tile (wave-uniform)

  stage(0, 0);
  __syncthreads();
  int buf = 0;
  for (int j=0; j<=jmaxb; ++j){
    if (j < jmaxb) stage(j+1, buf^1);
    if (j <= jmaxw){
      int kv0 = j*64;
      f32x4 sf[4];
      #pragma unroll
      for (int fj=0;fj<4;++fj) sf[fj] = zero;
      __builtin_amdgcn_s_setprio(1);
      #pragma unroll
      for (int ks=0;ks<4;++ks){
        #pragma unroll
        for (int fj=0;fj<4;++fj){
          int kvrow = fj*16 + c;
          bf16x8 kb = *(const bf16x8*)&Ks[buf][kvrow*128 + (((ks*4+g) ^ (c&7))*8)];
          sf[fj] = __builtin_amdgcn_mfma_f32_16x16x32_bf16(kb, qf[ks], sf[fj], 0,0,0);
        }
      }
      __builtin_amdgcn_s_setprio(0);
      if (j == jmaxw){
        int q = qw + c;
        #pragma unroll
        for (int fj=0;fj<4;++fj)
          #pragma unroll
          for (int rr=0;rr<4;++rr)
            if ((kv0 + fj*16 + g*4 + rr) > q) sf[fj][rr] = -1e30f;
      }
      f32x4 t4;
      #pragma unroll
      for (int rr=0;rr<4;++rr)
        t4[rr] = fmaxf(fmaxf(sf[0][rr], sf[1][rr]), fmaxf(sf[2][rr], sf[3][rr]));
      float rmax = fmaxf(fmaxf(t4[0], t4[1]), fmaxf(t4[2], t4[3]));
      rmax = fmaxf(rmax, __shfl_xor(rmax, 16));
      rmax = fmaxf(rmax, __shfl_xor(rmax, 32));
      if (__any(rmax > m_r + 8.0f)){
        float mnew = fmaxf(m_r, rmax);
        float alpha = exp2f(m_r - mnew);
        m_r = mnew;
        l_r *= alpha;
        float a4[4];
        #pragma unroll
        for (int rr=0;rr<4;++rr) a4[rr] = __shfl(alpha, g*4 + rr);
        #pragma unroll
        for (int ni=0;ni<8;++ni){
          f32x4 t = o[ni];
          t[0]*=a4[0]; t[1]*=a4[1]; t[2]*=a4[2]; t[3]*=a4[3];
          o[ni] = t;
        }
      }
      float ps;
      {
        f32x4 s4;
        #pragma unroll
        for (int fj=0;fj<4;++fj)
          #pragma unroll
          for (int rr=0;rr<4;++rr)
            sf[fj][rr] = exp2f(sf[fj][rr] - m_r);
        #pragma unroll
        for (int rr=0;rr<4;++rr)
          s4[rr] = (sf[0][rr] + sf[1][rr]) + (sf[2][rr] + sf[3][rr]);
        ps = (s4[0] + s4[1]) + (s4[2] + s4[3]);
        ps += __shfl_xor(ps, 16);
        ps += __shfl_xor(ps, 32);
      }
      l_r += ps;
      #pragma unroll
      for (int fj=0;fj<4;++fj){
        short4 pk;
        pk.x = f2bf(sf[fj][0]); pk.y = f2bf(sf[fj][1]);
        pk.z = f2bf(sf[fj][2]); pk.w = f2bf(sf[fj][3]);
        *(short4*)&Ps[w][c][(fj*16 + g*4) ^ ((c&7)<<3)] = pk;
      }
      __builtin_amdgcn_s_setprio(1);
      #pragma unroll
      for (int ks=0;ks<2;++ks){
        bf16x8 pa = *(const bf16x8*)&Ps[w][c][(ks*32 + g*8) ^ ((c&7)<<3)];
        #pragma unroll
        for (int ni=0;ni<8;++ni){
          int d = ni*16 + c;
          bf16x8 vb = *(const bf16x8*)&Vs[buf][d*64 + (((ks*4+g) ^ (c&7))*8)];
          o[ni] = __builtin_amdgcn_mfma_f32_16x16x32_bf16(pa, vb, o[ni], 0,0,0);
        }
      }
      __builtin_amdgcn_s_setprio(0);
    }
    __syncthreads();   // drains stage(j+1) vmcnt + Ks/Vs reuse
    buf ^= 1;
  }
  int b = bh >> 5, h = bh & 31;
  float inv = 1.0f / l_r;
  float inv4[4];
  #pragma unroll
  for (int rr=0;rr<4;++rr) inv4[rr] = __shfl(inv, g*4 + rr);
  #pragma unroll
  for (int rr=0;rr<4;++rr){
    int s = qw + g*4 + rr;
    #pragma unroll
    for (int ni=0;ni<8;++ni){
      int d = ni*16 + c;
      attn[((size_t)(b*SEQ + s))*HID + h*HDIM + d] = f2bf(o[ni][rr] * inv4[rr]);
    }
  }
}

extern "C" void kernel_launch(void* const* d_in, const int* in_sizes, int n_in,
                              void* d_out, int out_size, void* d_ws, size_t ws_size,
                              hipStream_t stream){
  const float* hs   = (const float*)d_in[0];
  const int*   pos  = (const int*)d_in[1];
  const float* wqkv = (const float*)d_in[2];
  const float* wo   = (const float*)d_in[3];
  float* out = (float*)d_out;
  char* ws = (char*)d_ws;
  size_t off = 0;
  auto alloc = [&](size_t bytes){ void* p = ws + off; off += (bytes + 255) & ~(size_t)255; return p; };
  short* hsb   = (short*)alloc((size_t)MROWS*HID*2);
  short* wqkvb = (short*)alloc((size_t)3*HID*HID*2);
  short* wob   = (short*)alloc((size_t)HID*HID*2);
  short* Qb    = (short*)alloc((size_t)BH*SEQ*HDIM*2);
  short* Kb    = (short*)alloc((size_t)BH*SEQ*HDIM*2);
  short* Vb    = (short*)alloc((size_t)BH*SEQ*HDIM*2);
  short* Vt    = (short*)alloc((size_t)BH*SEQ*HDIM*2);
  short* attn  = (short*)alloc((size_t)MROWS*HID*2);
  float* tab   = (float*)alloc((size_t)SEQ*64*2*4);
  (void)ws_size; (void)in_sizes; (void)n_in; (void)out_size;

  cvt3_bf16<<<2048,256,0,stream>>>(hs, hsb, MROWS*HID/4,
                                   wqkv, wqkvb, 3*HID*HID/4,
                                   wo, wob, HID*HID/4);
  rope_table_k<<<(SEQ*64+255)/256,256,0,stream>>>(pos, tab);
  gemm8r<0><<<dim3(48,16),512,0,stream>>>(hsb, wqkvb, Qb, Kb, Vb, nullptr);
  rope_apply_k<<<(BH*SEQ*8+255)/256,256,0,stream>>>(Qb, Kb, tab);
  transpose_v_k<<<dim3(SEQ/64, HDIM/64, BH),256,0,stream>>>(Vb, Vt);
  flash_attn_k<<<dim3(BH*16),512,0,stream>>>(Qb, Kb, Vt, attn);
  gemm8r<1><<<dim3(16,16),512,0,stream>>>(attn, wob, nullptr, nullptr, nullptr, out);
}

// Round 16
// 705.839 us; speedup vs baseline: 1.1522x; 1.0563x over previous
//
#include <hip/hip_runtime.h>
#include <hip/hip_bf16.h>

#define BATCH 2
#define SEQ 2048
#define HID 4096
#define NHEAD 32
#define HDIM 128
#define BH (BATCH*NHEAD)   /* 64 */
#define MROWS (BATCH*SEQ)  /* 4096 */
#define SC2 0.1275187963f   /* (1/sqrt(128)) * log2(e), folded into Q in rope */

typedef __attribute__((ext_vector_type(8))) short bf16x8;
typedef __attribute__((ext_vector_type(4))) float f32x4;

__device__ __forceinline__ float bf2f(short x){
  union { float f; unsigned u; } v; v.u = ((unsigned)(unsigned short)x) << 16; return v.f;
}
__device__ __forceinline__ short f2bf(float f){
  __hip_bfloat16 h = __float2bfloat16(f);   // native RNE convert
  return *(short*)&h;
}
__device__ __forceinline__ void gload_lds16(const void* g, void* l){
  __builtin_amdgcn_global_load_lds(
    (const __attribute__((address_space(1))) void*)g,
    (__attribute__((address_space(3))) void*)l, 16, 0, 0);
}

// ---------------- fused f32 -> bf16 convert (3 tensors) ----------------
__global__ void cvt3_bf16(const float* __restrict__ a, short* __restrict__ ao, int na4,
                          const float* __restrict__ b, short* __restrict__ bo, int nb4,
                          const float* __restrict__ cc, short* __restrict__ co, int nc4){
  int i = blockIdx.x*blockDim.x + threadIdx.x;
  int stride = gridDim.x*blockDim.x;
  int tot = na4 + nb4 + nc4;
  for (; i < tot; i += stride){
    const float* src; short* dst; int k = i;
    if (k < na4){ src=a; dst=ao; }
    else if (k < na4+nb4){ k -= na4; src=b; dst=bo; }
    else { k -= na4+nb4; src=cc; dst=co; }
    float4 v = ((const float4*)src)[k];
    short4 o;
    o.x = f2bf(v.x); o.y = f2bf(v.y); o.z = f2bf(v.z); o.w = f2bf(v.w);
    ((short4*)dst)[k] = o;
  }
}

// ---------------- RoPE cos/sin table ----------------
__global__ void rope_table_k(const int* __restrict__ pos, float* __restrict__ tab){
  int idx = blockIdx.x*blockDim.x + threadIdx.x;
  if (idx >= SEQ*64) return;
  int s = idx >> 6, d = idx & 63;
  float p = (float)pos[s];
  float inv = exp2f(-(float)d * (13.287712379549449f/64.0f)); // 10000^(-d/64)
  float ang = p * inv;
  tab[2*idx]   = cosf(ang);
  tab[2*idx+1] = sinf(ang);
}

// ===== 256x256 8-phase GEMM, r5 reads/stages/vmcnt; NO blanket lgkmcnt(0) —
// plain-C++ ds_reads let the compiler emit fine-grained counted lgkm waits
// (m97-proven); blanket drain was an asm-read idiom we don't need. =====
template<int W>
__device__ __forceinline__ void stage_half(const short* __restrict__ gsrc, int ldg,
                                           short* lds, int tid, int h){
  #pragma unroll
  for (int li=0; li<2; ++li){
    int e16 = li*512 + tid;
    int rs = e16 >> 3, ck = e16 & 7;
    int r = ((rs/W)*2 + h)*W + (rs%W);
    gload_lds16(gsrc + (size_t)r*ldg + ((ck ^ (r&7))<<3),
                lds + r*64 + ck*8);
  }
}

__device__ __forceinline__ void read_ahalf(const short* Asb, int wr, int c, int g,
                                           int Mh, bf16x8 (&afr)[4][2]){
  #pragma unroll
  for (int mi=0; mi<4; ++mi){
    int row = wr*128 + (Mh*4+mi)*16 + c;
    const char* bp = (const char*)Asb + row*128;
    #pragma unroll
    for (int kk=0; kk<2; ++kk)
      afr[mi][kk] = *(const bf16x8*)(bp + ((kk*64 + g*16) ^ ((row&7)<<4)));
  }
}
__device__ __forceinline__ void read_bhalf(const short* Bsb, int wc, int c, int g,
                                           int Nh, bf16x8 (&bfr)[2][2]){
  #pragma unroll
  for (int ni=0; ni<2; ++ni){
    int row = wc*64 + (Nh*2+ni)*16 + c;
    const char* bp = (const char*)Bsb + row*128;
    #pragma unroll
    for (int kk=0; kk<2; ++kk)
      bfr[ni][kk] = *(const bf16x8*)(bp + ((kk*64 + g*16) ^ ((row&7)<<4)));
  }
}
template<int MH, int NHH>
__device__ __forceinline__ void mma_q(bf16x8 (&afr)[4][2], bf16x8 (&bfr)[2][2],
                                      f32x4 (&acc)[8][4]){
  #pragma unroll
  for (int kk=0; kk<2; ++kk)
    #pragma unroll
    for (int mi=0; mi<4; ++mi)
      #pragma unroll
      for (int ni=0; ni<2; ++ni)
        acc[MH*4+mi][NHH*2+ni] = __builtin_amdgcn_mfma_f32_16x16x32_bf16(
            afr[mi][kk], bfr[ni][kk], acc[MH*4+mi][NHH*2+ni], 0,0,0);
}

#define BAR()  asm volatile("s_barrier" ::: "memory")
#define VMC6() asm volatile("s_waitcnt vmcnt(6)" ::: "memory")
#define VMC8() asm volatile("s_waitcnt vmcnt(8)" ::: "memory")
#define VMC0() asm volatile("s_waitcnt vmcnt(0)" ::: "memory")
#define SP1()  __builtin_amdgcn_s_setprio(1)
#define SP0()  __builtin_amdgcn_s_setprio(0)

// MODE 0: QKV proj -> clip +-8 -> scatter bf16 into Q/K/V [BH][S][HD]
// MODE 1: O proj -> f32 row-major out
template<int MODE>
__global__ __launch_bounds__(512, 2) void gemm8r(
    const short* __restrict__ A, const short* __restrict__ Bw,
    short* __restrict__ Qb, short* __restrict__ Kb, short* __restrict__ Vb,
    float* __restrict__ Of){
  __shared__ __align__(16) short As[2][256*64];
  __shared__ __align__(16) short Bs[2][256*64];
  const int K = HID;
  int tid = threadIdx.x, lane = tid & 63, w = tid >> 6;
  int wr = w >> 2, wc = w & 3, g = lane >> 4, c = lane & 15;
  int gx = gridDim.x;
  int nwg = gx * gridDim.y;
  int bid = blockIdx.y*gx + blockIdx.x;
  int cpx = nwg >> 3;
  int swz = (bid & 7)*cpx + (bid >> 3);
  int m0 = (swz / gx) * 256, n0 = (swz % gx) * 256;

  const short* Abase = A  + (size_t)m0*K;
  const short* Bbase = Bw + (size_t)n0*K;
  auto stageA = [&](int buf, int kt, int h){
    stage_half<64>(Abase + kt*64, K, &As[buf][0], tid, h);
  };
  auto stageB = [&](int buf, int kt, int h){
    stage_half<32>(Bbase + kt*64, K, &Bs[buf][0], tid, h);
  };

  f32x4 acc[8][4];
  f32x4 zero = {0.f,0.f,0.f,0.f};
  #pragma unroll
  for (int i=0;i<8;++i)
    #pragma unroll
    for (int j=0;j<4;++j) acc[i][j] = zero;
  bf16x8 afr[4][2], bfr0[2][2], bfr1[2][2];

  stageB(0,0,0); stageB(0,0,1); stageA(0,0,0); stageA(0,0,1);
  stageB(1,1,0); stageB(1,1,1); stageA(1,1,0); stageA(1,1,1);
  VMC8();
  BAR();

  const int NITER = K/128;  // 32 iterations, 2 K-tiles each
  for (int i = 0; i < NITER-1; ++i){
    int t2 = 2*i+2, t3 = 2*i+3;
    read_ahalf(&As[0][0], wr,c,g, 0, afr);
    read_bhalf(&Bs[0][0], wc,c,g, 0, bfr0);
    BAR(); SP1(); mma_q<0,0>(afr,bfr0,acc); SP0(); BAR();
    read_bhalf(&Bs[0][0], wc,c,g, 1, bfr1);
    stageB(0, t2, 0);
    BAR(); SP1(); mma_q<0,1>(afr,bfr1,acc); SP0(); BAR();
    read_ahalf(&As[0][0], wr,c,g, 1, afr);
    stageB(0, t2, 1); stageA(0, t2, 0);
    BAR(); SP1(); mma_q<1,1>(afr,bfr1,acc); SP0(); BAR();
    BAR(); SP1(); mma_q<1,0>(afr,bfr0,acc); SP0(); VMC6(); BAR();
    read_ahalf(&As[1][0], wr,c,g, 0, afr);
    read_bhalf(&Bs[1][0], wc,c,g, 0, bfr0);
    stageA(0, t2, 1);
    BAR(); SP1(); mma_q<0,0>(afr,bfr0,acc); SP0(); BAR();
    read_bhalf(&Bs[1][0], wc,c,g, 1, bfr1);
    stageB(1, t3, 0);
    BAR(); SP1(); mma_q<0,1>(afr,bfr1,acc); SP0(); BAR();
    read_ahalf(&As[1][0], wr,c,g, 1, afr);
    stageB(1, t3, 1); stageA(1, t3, 0);
    BAR(); SP1(); mma_q<1,1>(afr,bfr1,acc); SP0(); BAR();
    stageA(1, t3, 1);
    BAR(); SP1(); mma_q<1,0>(afr,bfr0,acc); SP0(); VMC8(); BAR();
  }
  {
    read_ahalf(&As[0][0], wr,c,g, 0, afr);
    read_bhalf(&Bs[0][0], wc,c,g, 0, bfr0);
    BAR(); SP1(); mma_q<0,0>(afr,bfr0,acc); SP0(); BAR();
    read_bhalf(&Bs[0][0], wc,c,g, 1, bfr1);
    BAR(); SP1(); mma_q<0,1>(afr,bfr1,acc); SP0(); BAR();
    read_ahalf(&As[0][0], wr,c,g, 1, afr);
    BAR(); SP1(); mma_q<1,1>(afr,bfr1,acc); SP0(); BAR();
    BAR(); SP1(); mma_q<1,0>(afr,bfr0,acc); SP0(); VMC0(); BAR();
    read_ahalf(&As[1][0], wr,c,g, 0, afr);
    read_bhalf(&Bs[1][0], wc,c,g, 0, bfr0);
    BAR(); SP1(); mma_q<0,0>(afr,bfr0,acc); SP0(); BAR();
    read_bhalf(&Bs[1][0], wc,c,g, 1, bfr1);
    BAR(); SP1(); mma_q<0,1>(afr,bfr1,acc); SP0(); BAR();
    read_ahalf(&As[1][0], wr,c,g, 1, afr);
    BAR(); SP1(); mma_q<1,1>(afr,bfr1,acc); SP0(); BAR();
    BAR(); SP1(); mma_q<1,0>(afr,bfr0,acc); SP0(); BAR();
  }

  #pragma unroll
  for (int fa=0; fa<8; ++fa){
    #pragma unroll
    for (int fb=0; fb<4; ++fb){
      f32x4 v = acc[fa][fb];
      #pragma unroll
      for (int rr=0; rr<4; ++rr){
        int row = m0 + wr*128 + fa*16 + g*4 + rr;
        int col = n0 + wc*64  + fb*16 + c;
        float x = v[rr];
        if (MODE == 0){
          x = fminf(fmaxf(x, -8.0f), 8.0f);
          int sel = col >> 12, wi = col & 4095;
          int head = wi >> 7, d = wi & 127;
          int b = row >> 11, s = row & 2047;
          size_t off = ((size_t)(b*NHEAD + head)*SEQ + s)*HDIM + d;
          short* dst = (sel == 0) ? Qb : (sel == 1) ? Kb : Vb;
          dst[off] = f2bf(x);
        } else {
          Of[(size_t)row*HID + col] = x;
        }
      }
    }
  }
}

// ---- RoPE in place on Q and K, vectorized; Q gets *SC2 (scale+log2e fold) ----
__global__ void rope_apply_k(short* __restrict__ Qb, short* __restrict__ Kb,
                             const float* __restrict__ tab){
  int idx = blockIdx.x*blockDim.x + threadIdx.x;
  if (idx >= BH*SEQ*8) return;
  int t = idx & 7;
  int s = (idx >> 3) & (SEQ-1);
  int bh = idx >> 14;
  size_t base = ((size_t)bh*SEQ + s)*HDIM + t*8;
  const float* tb = tab + 2*(s*64 + t*8);
  bf16x8 q1 = *(bf16x8*)(Qb+base), q2 = *(bf16x8*)(Qb+base+64);
  bf16x8 k1 = *(bf16x8*)(Kb+base), k2 = *(bf16x8*)(Kb+base+64);
  bf16x8 o1, o2, p1, p2;
  #pragma unroll
  for (int u=0;u<8;++u){
    float cs = tb[2*u], sn = tb[2*u+1];
    float a = bf2f(q1[u]), b = bf2f(q2[u]);
    o1[u] = f2bf((a*cs - b*sn)*SC2); o2[u] = f2bf((b*cs + a*sn)*SC2);
    a = bf2f(k1[u]); b = bf2f(k2[u]);
    p1[u] = f2bf(a*cs - b*sn); p2[u] = f2bf(b*cs + a*sn);
  }
  *(bf16x8*)(Qb+base)    = o1; *(bf16x8*)(Qb+base+64) = o2;
  *(bf16x8*)(Kb+base)    = p1; *(bf16x8*)(Kb+base+64) = p2;
}

// ---- V transpose: [BH][S][HD] -> Vt [BH][HD][S], 64x64 tiles, short4 both ways ----
__global__ void transpose_v_k(const short* __restrict__ V, short* __restrict__ Vt){
  __shared__ short t[64][68];
  int bh = blockIdx.z;
  int s0 = blockIdx.x*64, d0 = blockIdx.y*64;
  int q = threadIdx.x & 15, r4 = threadIdx.x >> 4;   // 16 quads x 16 row-groups
  const short* src = V + ((size_t)bh*SEQ + s0)*HDIM + d0;
  #pragma unroll
  for (int p=0;p<4;++p){
    int row = p*16 + r4;
    *(short4*)&t[row][q*4] = *(const short4*)&src[(size_t)row*HDIM + q*4];
  }
  __syncthreads();
  short* dst = Vt + ((size_t)bh*HDIM + d0)*SEQ + s0;
  #pragma unroll
  for (int p=0;p<4;++p){
    int drow = p*16 + r4;
    short4 v;
    v.x = t[q*4+0][drow]; v.y = t[q*4+1][drow];
    v.z = t[q*4+2][drow]; v.w = t[q*4+3][drow];
    *(short4*)&dst[(size_t)drow*SEQ + q*4] = v;
  }
}

// ======== Flash attention, causal, QBLK=128 / KVBLK=64, 8 waves, swapped QK^T ====
// Global LPT dispatch: flat = jqrank*64 + bhg*8 + xcd -> heaviest blocks first
// across ALL bh (bijective; preserves per-bh XCD clustering).
__global__ __launch_bounds__(512, 4) void flash_attn_k(
    const short* __restrict__ Qb, const short* __restrict__ Kb,
    const short* __restrict__ Vt, short* __restrict__ attn){
  __shared__ short Ks[2][64*128];   // 32 KB, chunk-swizzled
  __shared__ short Vs[2][128*64];   // 32 KB, chunk-swizzled
  __shared__ short Ps[8][16][64];   // 16 KB, XOR-swizzled
  int tid = threadIdx.x, lane = tid & 63, w = tid >> 6;
  int g = lane >> 4, c = lane & 15;
  int flat = blockIdx.x;
  int xcd = flat & 7, idx = flat >> 3;
  int bhg = idx & 7, jqrank = idx >> 3;
  int bh = xcd + 8*bhg;
  int jq = 15 - jqrank;             // global heavy-first (LPT)
  int qw = jq*128 + w*16;           // this wave's 16 q-rows
  bf16x8 qf[4];
  #pragma unroll
  for (int ks=0;ks<4;++ks)
    qf[ks] = *(const bf16x8*)(Qb + ((size_t)bh*SEQ + qw + c)*HDIM + ks*32 + g*8);
  f32x4 o[8];
  f32x4 zero = {0.f,0.f,0.f,0.f};
  #pragma unroll
  for (int i=0;i<8;++i) o[i] = zero;
  float m_r = -1e30f;   // running max for q-row = qw + c
  float l_r = 0.f;

  auto stage = [&](int j, int b){
    int kv0 = j*64;
    #pragma unroll
    for (int i=0;i<2;++i){
      int e = i*512 + tid;
      int kr = e >> 4, kc = e & 15;
      gload_lds16(Kb + ((size_t)bh*SEQ + kv0 + kr)*HDIM + (size_t)((kc ^ (kr&7))*8),
                  &Ks[b][kr*128 + kc*8]);
      int vr = e >> 3, vc = e & 7;
      gload_lds16(Vt + ((size_t)bh*HDIM + vr)*SEQ + kv0 + (size_t)((vc ^ (vr&7))*8),
                  &Vs[b][vr*64 + vc*8]);
    }
  };

  const int jmaxb = 2*jq + 1;       // block's last KV tile
  const int jmaxw = qw >> 6;        // this wave's diagonal tile (wave-uniform)

  stage(0, 0);
  __syncthreads();
  int buf = 0;
  for (int j=0; j<=jmaxb; ++j){
    if (j < jmaxb) stage(j+1, buf^1);
    if (j <= jmaxw){
      int kv0 = j*64;
      f32x4 sf[4];
      #pragma unroll
      for (int fj=0;fj<4;++fj) sf[fj] = zero;
      __builtin_amdgcn_s_setprio(1);
      #pragma unroll
      for (int ks=0;ks<4;++ks){
        #pragma unroll
        for (int fj=0;fj<4;++fj){
          int kvrow = fj*16 + c;
          bf16x8 kb = *(const bf16x8*)&Ks[buf][kvrow*128 + (((ks*4+g) ^ (c&7))*8)];
          sf[fj] = __builtin_amdgcn_mfma_f32_16x16x32_bf16(kb, qf[ks], sf[fj], 0,0,0);
        }
      }
      __builtin_amdgcn_s_setprio(0);
      if (j == jmaxw){
        int q = qw + c;
        #pragma unroll
        for (int fj=0;fj<4;++fj)
          #pragma unroll
          for (int rr=0;rr<4;++rr)
            if ((kv0 + fj*16 + g*4 + rr) > q) sf[fj][rr] = -1e30f;
      }
      f32x4 t4;
      #pragma unroll
      for (int rr=0;rr<4;++rr)
        t4[rr] = fmaxf(fmaxf(sf[0][rr], sf[1][rr]), fmaxf(sf[2][rr], sf[3][rr]));
      float rmax = fmaxf(fmaxf(t4[0], t4[1]), fmaxf(t4[2], t4[3]));
      rmax = fmaxf(rmax, __shfl_xor(rmax, 16));
      rmax = fmaxf(rmax, __shfl_xor(rmax, 32));
      if (__any(rmax > m_r + 8.0f)){
        float mnew = fmaxf(m_r, rmax);
        float alpha = exp2f(m_r - mnew);
        m_r = mnew;
        l_r *= alpha;
        float a4[4];
        #pragma unroll
        for (int rr=0;rr<4;++rr) a4[rr] = __shfl(alpha, g*4 + rr);
        #pragma unroll
        for (int ni=0;ni<8;++ni){
          f32x4 t = o[ni];
          t[0]*=a4[0]; t[1]*=a4[1]; t[2]*=a4[2]; t[3]*=a4[3];
          o[ni] = t;
        }
      }
      float ps;
      {
        f32x4 s4;
        #pragma unroll
        for (int fj=0;fj<4;++fj)
          #pragma unroll
          for (int rr=0;rr<4;++rr)
            sf[fj][rr] = exp2f(sf[fj][rr] - m_r);
        #pragma unroll
        for (int rr=0;rr<4;++rr)
          s4[rr] = (sf[0][rr] + sf[1][rr]) + (sf[2][rr] + sf[3][rr]);
        ps = (s4[0] + s4[1]) + (s4[2] + s4[3]);
        ps += __shfl_xor(ps, 16);
        ps += __shfl_xor(ps, 32);
      }
      l_r += ps;
      #pragma unroll
      for (int fj=0;fj<4;++fj){
        short4 pk;
        pk.x = f2bf(sf[fj][0]); pk.y = f2bf(sf[fj][1]);
        pk.z = f2bf(sf[fj][2]); pk.w = f2bf(sf[fj][3]);
        *(short4*)&Ps[w][c][(fj*16 + g*4) ^ ((c&7)<<3)] = pk;
      }
      __builtin_amdgcn_s_setprio(1);
      #pragma unroll
      for (int ks=0;ks<2;++ks){
        bf16x8 pa = *(const bf16x8*)&Ps[w][c][(ks*32 + g*8) ^ ((c&7)<<3)];
        #pragma unroll
        for (int ni=0;ni<8;++ni){
          int d = ni*16 + c;
          bf16x8 vb = *(const bf16x8*)&Vs[buf][d*64 + (((ks*4+g) ^ (c&7))*8)];
          o[ni] = __builtin_amdgcn_mfma_f32_16x16x32_bf16(pa, vb, o[ni], 0,0,0);
        }
      }
      __builtin_amdgcn_s_setprio(0);
    }
    __syncthreads();   // drains stage(j+1) vmcnt + Ks/Vs reuse
    buf ^= 1;
  }
  int b = bh >> 5, h = bh & 31;
  float inv = 1.0f / l_r;
  float inv4[4];
  #pragma unroll
  for (int rr=0;rr<4;++rr) inv4[rr] = __shfl(inv, g*4 + rr);
  #pragma unroll
  for (int rr=0;rr<4;++rr){
    int s = qw + g*4 + rr;
    #pragma unroll
    for (int ni=0;ni<8;++ni){
      int d = ni*16 + c;
      attn[((size_t)(b*SEQ + s))*HID + h*HDIM + d] = f2bf(o[ni][rr] * inv4[rr]);
    }
  }
}

extern "C" void kernel_launch(void* const* d_in, const int* in_sizes, int n_in,
                              void* d_out, int out_size, void* d_ws, size_t ws_size,
                              hipStream_t stream){
  const float* hs   = (const float*)d_in[0];
  const int*   pos  = (const int*)d_in[1];
  const float* wqkv = (const float*)d_in[2];
  const float* wo   = (const float*)d_in[3];
  float* out = (float*)d_out;
  char* ws = (char*)d_ws;
  size_t off = 0;
  auto alloc = [&](size_t bytes){ void* p = ws + off; off += (bytes + 255) & ~(size_t)255; return p; };
  short* hsb   = (short*)alloc((size_t)MROWS*HID*2);
  short* wqkvb = (short*)alloc((size_t)3*HID*HID*2);
  short* wob   = (short*)alloc((size_t)HID*HID*2);
  short* Qb    = (short*)alloc((size_t)BH*SEQ*HDIM*2);
  short* Kb    = (short*)alloc((size_t)BH*SEQ*HDIM*2);
  short* Vb    = (short*)alloc((size_t)BH*SEQ*HDIM*2);
  short* Vt    = (short*)alloc((size_t)BH*SEQ*HDIM*2);
  short* attn  = (short*)alloc((size_t)MROWS*HID*2);
  float* tab   = (float*)alloc((size_t)SEQ*64*2*4);
  (void)ws_size; (void)in_sizes; (void)n_in; (void)out_size;

  cvt3_bf16<<<2048,256,0,stream>>>(hs, hsb, MROWS*HID/4,
                                   wqkv, wqkvb, 3*HID*HID/4,
                                   wo, wob, HID*HID/4);
  rope_table_k<<<(SEQ*64+255)/256,256,0,stream>>>(pos, tab);
  gemm8r<0><<<dim3(48,16),512,0,stream>>>(hsb, wqkvb, Qb, Kb, Vb, nullptr);
  rope_apply_k<<<(BH*SEQ*8+255)/256,256,0,stream>>>(Qb, Kb, tab);
  transpose_v_k<<<dim3(SEQ/64, HDIM/64, BH),256,0,stream>>>(Vb, Vt);
  flash_attn_k<<<dim3(BH*16),512,0,stream>>>(Qb, Kb, Vt, attn);
  gemm8r<1><<<dim3(16,16),512,0,stream>>>(attn, wob, nullptr, nullptr, nullptr, out);
}